// Round 15
// baseline (4356.918 us; speedup 1.0000x reference)
//
#include <hip/hip_runtime.h>
#include <hip/hip_bf16.h>

// ---------------------------------------------------------------------------
// 2-layer LSTM (B=256,S=512,E=128,H=256) + LayerNorm + projection.
// Round 14: PERSISTENT pipeline kernel. R12/R13 counters gave
// stage = T*1.66us + 62us fixed (weight reload + state round-trip + launch)
// -- paid 9x. Now ONE 224-WG launch (32 scan + 192 helper WGs, all
// co-resident: 224 <= 256 CUs at 1 WG/CU) iterates all chunks:
//   phase 2s  : scan WGs step chunk s (A: L0) / s-1 (B: L1), weights+h+c
//               persistent in regs/LDS; helpers do embed+gemmA(s+1) -> xpA
//   barrier
//   phase 2s+1: helpers do gemmB: h1(s) -> xpB (384 teams, ~10us)
//   barrier
// Grid barriers = device-scope atomic counters + fences (R11-validated
// primitives; 18 barriers/launch, not per-step). Counters zeroed per launch.
// Scan body / layouts verbatim R9-R13 (passed, absmax 0.0156).
// ---------------------------------------------------------------------------

typedef unsigned short u16;
typedef unsigned int   u32;
using short8 = __attribute__((ext_vector_type(8))) short;
using f32x4  = __attribute__((ext_vector_type(4))) float;

#define NB 256
#define NS 512
#define NE 128
#define NH 256
#define NG 1024  // 4*H

#define WLDS_FRAGS 18
#define HOFF 147456
#define SCAN_LDS (HOFF + 2 * 16 * NH * 2)   // 163840 = 160 KiB

#define NSCAN 32
#define NHELP 192
#define NWG   (NSCAN + NHELP)

#define L2E     1.4426950408889634f
#define TWO_L2E 2.8853900817779268f

__device__ __forceinline__ u16 f2b(float x) {
  __hip_bfloat16 h = __float2bfloat16(x);
  return __builtin_bit_cast(u16, h);
}
__device__ __forceinline__ float b2f(u16 u) {
  return __builtin_bit_cast(float, (u32)u << 16);
}
__device__ __forceinline__ float ex2(float x)  { return __builtin_amdgcn_exp2f(x); }
__device__ __forceinline__ float ex2n(float x) { return __builtin_amdgcn_exp2f(-x); }
__device__ __forceinline__ float rcpa(float x) { return __builtin_amdgcn_rcpf(x); }

// ---- grid barrier: monotonic per-phase counter, device-scope ----
__device__ __forceinline__ void gbar(u32* bar, int ph, int tid) {
  __syncthreads();                     // all WG stores drained (vmcnt(0) at barrier)
  if (tid == 0) {
    __threadfence();                   // publish to device scope (L2 wb)
    __hip_atomic_fetch_add(bar + ph * 16, 1u, __ATOMIC_RELEASE, __HIP_MEMORY_SCOPE_AGENT);
    while (__hip_atomic_load(bar + ph * 16, __ATOMIC_ACQUIRE, __HIP_MEMORY_SCOPE_AGENT) < (u32)NWG)
      __builtin_amdgcn_s_sleep(8);
  }
  __syncthreads();                     // whole WG sees post-acquire state
}

// ---------------- prep: fp32 weights -> bf16 (exp2-prescaled), biases ------
__global__ __launch_bounds__(256) void prep_weights(
    const float* Wih0, const float* Whh0, const float* bih0, const float* bhh0,
    const float* Wih1, const float* Whh1, const float* bih1, const float* bhh1,
    u16* wih0b, u16* whh0b, u16* wih1b, u16* whh1b, float* bc0, float* bc1) {
  int stride = gridDim.x * blockDim.x;
  int tid = blockIdx.x * blockDim.x + threadIdx.x;
  for (int i = tid; i < NG * NE; i += stride) {
    float s = (((i >> 7) >> 8) == 2) ? TWO_L2E : L2E;
    wih0b[i] = f2b(Wih0[i] * s);
  }
  for (int i = tid; i < NG * NH; i += stride) {
    float s = (((i >> 8) >> 8) == 2) ? TWO_L2E : L2E;
    whh0b[i] = f2b(Whh0[i] * s);
    wih1b[i] = f2b(Wih1[i] * s);
    whh1b[i] = f2b(Whh1[i] * s);
  }
  for (int i = tid; i < NG; i += stride) {
    float s = ((i >> 8) == 2) ? TWO_L2E : L2E;
    bc0[i] = (bih0[i] + bhh0[i]) * s;
    bc1[i] = (bih1[i] + bhh1[i]) * s;
  }
}

__global__ __launch_bounds__(256) void zero_flags(u32* f, int n) {
  int i = blockIdx.x * 256 + threadIdx.x;
  if (i < n) f[i] = 0;
}

// ---------------- embedding gather (prologue chunk 0 only) -----------------
__global__ __launch_bounds__(256) void embed_chunk(const int* __restrict__ x,
                                                   const float* __restrict__ emb,
                                                   u16* __restrict__ ebuf, int t0) {
  int gid = blockIdx.x * 256 + threadIdx.x;
  int d4 = gid & 31;
  int sb = gid >> 5;
  int b  = sb & (NB - 1);
  int sl = sb >> 8;
  int tok = x[b * NS + (t0 + sl)];
  float4 v = make_float4(0.f, 0.f, 0.f, 0.f);
  if (tok != 0) v = *(const float4*)(emb + (size_t)tok * NE + d4 * 4);
  ushort4 o;
  o.x = f2b(v.x); o.y = f2b(v.y); o.z = f2b(v.z); o.w = f2b(v.w);
  *(ushort4*)(ebuf + (size_t)sb * NE + d4 * 4) = o;
}

// ---------------- xp GEMM (prologue chunk 0 only) --------------------------
template <int K>
__global__ __launch_bounds__(256) void xp_gemm(const u16* __restrict__ A,
                                               const u16* __restrict__ W,
                                               const float* __restrict__ bias,
                                               u16* __restrict__ Cout) {
  __shared__ __align__(16) char lds[2 * 128 * 80];
  char* Asm = lds;
  char* Bsm = lds + 128 * 80;
  int tid = threadIdx.x;
  int w = tid >> 6, l = tid & 63;
  int hi = l >> 4, lo = l & 15;
  int mblk = blockIdx.x >> 3, nblk = blockIdx.x & 7;
  size_t arow0 = (size_t)mblk * 128;
  int g0 = nblk * 128;
  int wm = (w >> 1) * 64, wn = (w & 1) * 64;
  f32x4 acc[4][4] = {};
  int r = tid >> 1, cp = tid & 1;

  for (int k0 = 0; k0 < K; k0 += 32) {
    int4 a0 = *(const int4*)(A + (arow0 + r) * K + k0 + cp * 16);
    int4 a1 = *(const int4*)(A + (arow0 + r) * K + k0 + cp * 16 + 8);
    int4 b0 = *(const int4*)(W + (size_t)(g0 + r) * K + k0 + cp * 16);
    int4 b1 = *(const int4*)(W + (size_t)(g0 + r) * K + k0 + cp * 16 + 8);
    *(int4*)(Asm + r * 80 + cp * 32)      = a0;
    *(int4*)(Asm + r * 80 + cp * 32 + 16) = a1;
    *(int4*)(Bsm + r * 80 + cp * 32)      = b0;
    *(int4*)(Bsm + r * 80 + cp * 32 + 16) = b1;
    __syncthreads();
    short8 af[4], bfr[4];
#pragma unroll
    for (int mt = 0; mt < 4; ++mt)
      af[mt] = *(const short8*)(Asm + (wm + mt * 16 + lo) * 80 + hi * 16);
#pragma unroll
    for (int nt = 0; nt < 4; ++nt)
      bfr[nt] = *(const short8*)(Bsm + (wn + nt * 16 + lo) * 80 + hi * 16);
#pragma unroll
    for (int mt = 0; mt < 4; ++mt)
#pragma unroll
      for (int nt = 0; nt < 4; ++nt)
        acc[mt][nt] = __builtin_amdgcn_mfma_f32_16x16x32_bf16(af[mt], bfr[nt], acc[mt][nt], 0, 0, 0);
    __syncthreads();
  }
#pragma unroll
  for (int nt = 0; nt < 4; ++nt) {
    int gc = g0 + wn + nt * 16 + lo;
    float bv = bias[gc];
    int ws_ = (gc >> 4) & 7, mts = gc >> 7, his = (gc >> 2) & 3, rs = gc & 3;
    size_t gbase = ((size_t)(ws_ * 8 + mts) << 8) + (size_t)(his * 16) * 4 + rs;
#pragma unroll
    for (int mt = 0; mt < 4; ++mt) {
      size_t row = arow0 + wm + mt * 16 + hi * 4;
#pragma unroll
      for (int rr = 0; rr < 4; ++rr) {
        size_t rw = row + rr;
        int t = (int)(rw >> 8), ba = (int)(rw & 255);
        size_t e = ((size_t)(t * 16 + (ba >> 4)) << 14) + gbase + (size_t)(ba & 15) * 4;
        Cout[e] = f2b(acc[mt][nt][rr] + bv);
      }
    }
  }
}

// ---------------- persistent pipeline kernel -------------------------------
__global__ __launch_bounds__(512, 2)
void lstm_persist(const int* __restrict__ x, const float* __restrict__ emb,
                  const u16* __restrict__ wih0b, const float* __restrict__ bc0,
                  const u16* __restrict__ whh0b, const u16* __restrict__ whh1b,
                  const u16* __restrict__ wih1b, const float* __restrict__ bc1,
                  u16* __restrict__ xpA0, u16* __restrict__ xpA1,
                  u16* __restrict__ xpB, u16* __restrict__ iobuf,
                  float* __restrict__ hs1, u32* __restrict__ bar,
                  int T, int nch) {
  extern __shared__ __align__(16) char smem[];
  int bid = blockIdx.x;
  int tid = threadIdx.x;

  if (bid >= NSCAN) {
    // ================= helper WGs: role C (embed+gemmA) then gemmB =========
    int team = tid >> 8, tt = tid & 255;
    char* Asm = smem + team * 40960;
    char* Bsm = Asm + 20480;
    int wq = tt >> 6, lq = tt & 63;
    int hiq = lq >> 4, loq = lq & 15;
    int wm = (wq >> 1) * 64, wn = (wq & 1) * 64;
    int r = tt >> 1, cp = tt & 1;
    int tg = (bid - NSCAN) * 2 + team;
    const int stride = NHELP * 2;
    int njobs = T * 16;
    int nIt = (njobs + stride - 1) / stride;

    for (int s = 0; s <= nch; ++s) {
      // ---- phase 2s: role C -> xpA[(s+1)&1] for chunk s+1 ----
      if (s + 1 < nch) {
        u16* xpC = ((s + 1) & 1) ? xpA1 : xpA0;
        int t0c = (s + 1) * T;
        for (int it = 0; it < nIt; ++it) {
          int j = tg + it * stride;
          bool act = j < njobs;
          int jj = act ? j : 0;
          int mblk = jj >> 3, nblk = jj & 7;
          size_t arow0 = (size_t)mblk * 128;
          int g0 = nblk * 128;
          f32x4 acc[4][4] = {};
          int rw = (int)(arow0 + r);
          int sl = rw >> 8, ba = rw & 255;
          int tok = x[ba * NS + t0c + sl];
          const float* erow = emb + (size_t)tok * NE;
          for (int k0 = 0; k0 < NE; k0 += 32) {
            const float* src = erow + k0 + cp * 16;
            u32 pk[8];
#pragma unroll
            for (int q = 0; q < 8; ++q) {
              float a = src[2 * q], b = src[2 * q + 1];
              if (tok == 0) { a = 0.0f; b = 0.0f; }
              pk[q] = (u32)f2b(a) | ((u32)f2b(b) << 16);
            }
            *(int4*)(Asm + r * 80 + cp * 32)      = *(int4*)&pk[0];
            *(int4*)(Asm + r * 80 + cp * 32 + 16) = *(int4*)&pk[4];
            int4 b0 = *(const int4*)(wih0b + (size_t)(g0 + r) * NE + k0 + cp * 16);
            int4 b1 = *(const int4*)(wih0b + (size_t)(g0 + r) * NE + k0 + cp * 16 + 8);
            *(int4*)(Bsm + r * 80 + cp * 32)      = b0;
            *(int4*)(Bsm + r * 80 + cp * 32 + 16) = b1;
            __syncthreads();
            short8 af[4], bfr[4];
#pragma unroll
            for (int mt = 0; mt < 4; ++mt)
              af[mt] = *(const short8*)(Asm + (wm + mt * 16 + loq) * 80 + hiq * 16);
#pragma unroll
            for (int nt = 0; nt < 4; ++nt)
              bfr[nt] = *(const short8*)(Bsm + (wn + nt * 16 + loq) * 80 + hiq * 16);
#pragma unroll
            for (int mt = 0; mt < 4; ++mt)
#pragma unroll
              for (int nt = 0; nt < 4; ++nt)
                acc[mt][nt] = __builtin_amdgcn_mfma_f32_16x16x32_bf16(af[mt], bfr[nt], acc[mt][nt], 0, 0, 0);
            __syncthreads();
          }
          if (act) {
#pragma unroll
            for (int nt = 0; nt < 4; ++nt) {
              int gc = g0 + wn + nt * 16 + loq;
              float bv = bc0[gc];
              int ws_ = (gc >> 4) & 7, mts = gc >> 7, his = (gc >> 2) & 3, rs = gc & 3;
              size_t gbase = ((size_t)(ws_ * 8 + mts) << 8) + (size_t)(his * 16) * 4 + rs;
#pragma unroll
              for (int mt = 0; mt < 4; ++mt) {
                size_t row = arow0 + wm + mt * 16 + hiq * 4;
#pragma unroll
                for (int rr = 0; rr < 4; ++rr) {
                  size_t rw2 = row + rr;
                  int t = (int)(rw2 >> 8), ba2 = (int)(rw2 & 255);
                  size_t e = ((size_t)(t * 16 + (ba2 >> 4)) << 14) + gbase + (size_t)(ba2 & 15) * 4;
                  xpC[e] = f2b(acc[mt][nt][rr] + bv);
                }
              }
            }
          }
        }
      }
      gbar(bar, 2 * s, tid);
      // ---- phase 2s+1: gemmB  h1(s)(iobuf) -> xpB ----
      if (s < nch) {
        for (int it = 0; it < nIt; ++it) {
          int j = tg + it * stride;
          bool act = j < njobs;
          int jj = act ? j : 0;
          int mblk = jj >> 3, nblk = jj & 7;
          size_t arow0 = (size_t)mblk * 128;
          int g0 = nblk * 128;
          f32x4 acc[4][4] = {};
          for (int k0 = 0; k0 < NH; k0 += 32) {
            int4 a0 = *(const int4*)(iobuf + (arow0 + r) * NH + k0 + cp * 16);
            int4 a1 = *(const int4*)(iobuf + (arow0 + r) * NH + k0 + cp * 16 + 8);
            int4 b0 = *(const int4*)(wih1b + (size_t)(g0 + r) * NH + k0 + cp * 16);
            int4 b1 = *(const int4*)(wih1b + (size_t)(g0 + r) * NH + k0 + cp * 16 + 8);
            *(int4*)(Asm + r * 80 + cp * 32)      = a0;
            *(int4*)(Asm + r * 80 + cp * 32 + 16) = a1;
            *(int4*)(Bsm + r * 80 + cp * 32)      = b0;
            *(int4*)(Bsm + r * 80 + cp * 32 + 16) = b1;
            __syncthreads();
            short8 af[4], bfr[4];
#pragma unroll
            for (int mt = 0; mt < 4; ++mt)
              af[mt] = *(const short8*)(Asm + (wm + mt * 16 + loq) * 80 + hiq * 16);
#pragma unroll
            for (int nt = 0; nt < 4; ++nt)
              bfr[nt] = *(const short8*)(Bsm + (wn + nt * 16 + loq) * 80 + hiq * 16);
#pragma unroll
            for (int mt = 0; mt < 4; ++mt)
#pragma unroll
              for (int nt = 0; nt < 4; ++nt)
                acc[mt][nt] = __builtin_amdgcn_mfma_f32_16x16x32_bf16(af[mt], bfr[nt], acc[mt][nt], 0, 0, 0);
            __syncthreads();
          }
          if (act) {
#pragma unroll
            for (int nt = 0; nt < 4; ++nt) {
              int gc = g0 + wn + nt * 16 + loq;
              float bv = bc1[gc];
              int ws_ = (gc >> 4) & 7, mts = gc >> 7, his = (gc >> 2) & 3, rs = gc & 3;
              size_t gbase = ((size_t)(ws_ * 8 + mts) << 8) + (size_t)(his * 16) * 4 + rs;
#pragma unroll
              for (int mt = 0; mt < 4; ++mt) {
                size_t row = arow0 + wm + mt * 16 + hiq * 4;
#pragma unroll
                for (int rr = 0; rr < 4; ++rr) {
                  size_t rw2 = row + rr;
                  int t = (int)(rw2 >> 8), ba2 = (int)(rw2 & 255);
                  size_t e = ((size_t)(t * 16 + (ba2 >> 4)) << 14) + gbase + (size_t)(ba2 & 15) * 4;
                  xpB[e] = f2b(acc[mt][nt][rr] + bv);
                }
              }
            }
          }
        }
      }
      gbar(bar, 2 * s + 1, tid);
    }
    return;
  }

  // ================= scan WGs: role A (L0) / role B (L1), persistent =======
  int roleB = bid >> 4;
  int bgi = bid & 15;
  int bg = bgi * 16;
  const u16* whh = roleB ? whh1b : whh0b;

  int w = tid >> 6, l = tid & 63;
  int hi = l >> 4, lo = l & 15;

  // ---- load Whh into regs + LDS (ONCE for the whole sequence) ----
  int wbase = w * (WLDS_FRAGS * 1024) + l * 16;
  short8 wfv[8][5];
  short8 wfv2[6];
#pragma unroll
  for (int mt = 0; mt < 8; ++mt) {
#pragma unroll
    for (int p = 0; p < 8; ++p) {
      const u16* src = whh + (size_t)(16 * (w + 8 * mt) + lo) * NH + p * 32 + hi * 8;
      short8 v = *(const short8*)src;
      if (p < 2)                 *(short8*)(smem + wbase + (p * 8 + mt) * 1024) = v;
      else if (p == 2 && mt < 2) *(short8*)(smem + wbase + (16 + mt) * 1024) = v;
      else if (p == 2)           wfv2[mt - 2] = v;
      else                       wfv[mt][p - 3] = v;
    }
  }
  // ---- init h = 0 (LDS buffer 0), c = 0 (ONCE) ----
  float c[2][4];
  for (int i = tid; i < 16 * NH / 2; i += 512) ((u32*)(smem + HOFF))[i] = 0;
#pragma unroll
  for (int g = 0; g < 2; ++g)
#pragma unroll
    for (int r = 0; r < 4; ++r) c[g][r] = 0.0f;
  __syncthreads();

  // ---- step-invariant offsets ----
  int rdoff = (l ^ ((l >> 3) & 7)) * 16;
  int wroff[2];
#pragma unroll
  for (int g = 0; g < 2; ++g) {
    int xx = (2 * (w & 1) + (hi >> 1)) * 16 + lo;
    wroff[g] = (4 * g + (w >> 1)) * 1024 + (xx ^ ((xx >> 3) & 7)) * 16 + 8 * (hi & 1);
  }
  int bq = tid >> 5, kc = tid & 31;
  int xw = (kc & 3) * 16 + bq;
  int wboff = (kc >> 2) * 1024 + (xw ^ ((xw >> 3) & 7)) * 16;
  size_t wb_glob = (size_t)(bg + bq) * NH + kc * 8;

  f32x4 acc[8];
  for (int s = 0; s <= nch; ++s) {
    bool act = roleB ? (s >= 1) : (s < nch);
    if (act) {
      int mc = roleB ? (s - 1) : s;
      const u16* xp = roleB ? xpB : ((mc & 1) ? xpA1 : xpA0);
      u16* hout = roleB ? (u16*)0 : iobuf;
      const u16* xpp = xp + ((size_t)(bgi * 8 + w) * 2048) + (size_t)l * 4;
      ushort4 xq[8];
#pragma unroll
      for (int mt = 0; mt < 8; ++mt) xq[mt] = *(const ushort4*)(xpp + mt * 256);

      for (int t = 0; t < T; ++t) {
        int rbase = HOFF + ((t & 1) << 13);
        int wbbase = HOFF + ((~t & 1) << 13);
#pragma unroll
        for (int mt = 0; mt < 8; ++mt) {
          f32x4 a;
          a[0] = b2f(xq[mt].x); a[1] = b2f(xq[mt].y);
          a[2] = b2f(xq[mt].z); a[3] = b2f(xq[mt].w);
          acc[mt] = a;
        }
        xpp += 262144;   // next t (final overrun: adjacent ws buffer, discarded)
#pragma unroll
        for (int mt = 0; mt < 8; ++mt) xq[mt] = *(const ushort4*)(xpp + mt * 256);
#pragma unroll
        for (int p = 0; p < 8; ++p) {
          short8 bf = *(const short8*)(smem + rbase + rdoff + p * 1024);
#pragma unroll
          for (int mt = 0; mt < 8; ++mt) {
            short8 af;
            if (p < 2)                 af = *(const short8*)(smem + wbase + (p * 8 + mt) * 1024);
            else if (p == 2 && mt < 2) af = *(const short8*)(smem + wbase + (16 + mt) * 1024);
            else if (p == 2)           af = wfv2[mt - 2];
            else                       af = wfv[mt][p - 3];
            acc[mt] = __builtin_amdgcn_mfma_f32_16x16x32_bf16(af, bf, acc[mt], 0, 0, 0);
          }
        }
#pragma unroll
        for (int g = 0; g < 2; ++g) {
          float hv[4];
#pragma unroll
          for (int r = 0; r < 4; ++r) {
            float iv = rcpa(1.0f + ex2n(acc[g][r]));
            float fv = rcpa(1.0f + ex2n(acc[2 + g][r]));
            float gv = 1.0f - 2.0f * rcpa(ex2(acc[4 + g][r]) + 1.0f);
            float ov = rcpa(1.0f + ex2n(acc[6 + g][r]));
            float cc = fv * c[g][r] + iv * gv;
            c[g][r] = cc;
            float th = 1.0f - 2.0f * rcpa(ex2(cc * TWO_L2E) + 1.0f);
            hv[r] = ov * th;
          }
          u32 d0, d1;
          asm("v_cvt_pk_bf16_f32 %0, %1, %2" : "=v"(d0) : "v"(hv[0]), "v"(hv[1]));
          asm("v_cvt_pk_bf16_f32 %0, %1, %2" : "=v"(d1) : "v"(hv[2]), "v"(hv[3]));
          uint2 hw; hw.x = d0; hw.y = d1;
          *(uint2*)(smem + wbbase + wroff[g]) = hw;
        }
        __syncthreads();
        if (hout) {
          int4 hv4 = *(const int4*)(smem + wbbase + wboff);
          *(int4*)(hout + wb_glob + ((size_t)t << 16)) = hv4;
        }
      }
    }
    gbar(bar, 2 * s, tid);
    gbar(bar, 2 * s + 1, tid);
  }

  // ---- role B: final h -> hs1 for ln_proj (T even => final h in buf 0) ----
  if (roleB) {
#pragma unroll
    for (int g = 0; g < 2; ++g) {
      ushort4 hv4 = *(const ushort4*)(smem + HOFF + wroff[g]);
      int j = 16 * w + 128 * g + 4 * hi;
      u16 hb[4] = {hv4.x, hv4.y, hv4.z, hv4.w};
#pragma unroll
      for (int r = 0; r < 4; ++r)
        hs1[(size_t)(bg + lo) * NH + j + r] = b2f(hb[r]);
    }
  }
}

// ---------------- LayerNorm + projection -----------------------------------
__global__ __launch_bounds__(256) void ln_proj(const float* __restrict__ hn,
                                               const float* __restrict__ lng,
                                               const float* __restrict__ lnb,
                                               const float* __restrict__ pW,
                                               const float* __restrict__ pb,
                                               float* __restrict__ out) {
  __shared__ __align__(16) float nbuf[NH];
  __shared__ float red[8];
  int b = blockIdx.x, tid = threadIdx.x;
  float v = hn[(size_t)b * NH + tid];
  float s = v, s2 = v * v;
#pragma unroll
  for (int o = 32; o > 0; o >>= 1) {
    s  += __shfl_down(s, o);
    s2 += __shfl_down(s2, o);
  }
  if ((tid & 63) == 0) { red[tid >> 6] = s; red[4 + (tid >> 6)] = s2; }
  __syncthreads();
  if (tid == 0) {
    red[0] = red[0] + red[1] + red[2] + red[3];
    red[4] = red[4] + red[5] + red[6] + red[7];
  }
  __syncthreads();
  float mean = red[0] * (1.0f / NH);
  float var  = red[4] * (1.0f / NH) - mean * mean;
  float rs = rsqrtf(var + 1e-5f);
  nbuf[tid] = (v - mean) * rs * lng[tid] + lnb[tid];
  __syncthreads();
  if (tid < NE) {
    float a = pb[tid];
    const float* wr = pW + (size_t)tid * NH;
#pragma unroll 4
    for (int j = 0; j < NH; ++j) a = fmaf(nbuf[j], wr[j], a);
    out[(size_t)b * NE + tid] = a;
  }
}

// ---------------------------------------------------------------------------
extern "C" void kernel_launch(void* const* d_in, const int* in_sizes, int n_in,
                              void* d_out, int out_size, void* d_ws, size_t ws_size,
                              hipStream_t stream) {
  const int*   x     = (const int*)d_in[0];
  const float* emb   = (const float*)d_in[1];
  const float* Wih0  = (const float*)d_in[2];
  const float* Whh0  = (const float*)d_in[3];
  const float* bih0  = (const float*)d_in[4];
  const float* bhh0  = (const float*)d_in[5];
  const float* Wih1  = (const float*)d_in[6];
  const float* Whh1  = (const float*)d_in[7];
  const float* bih1  = (const float*)d_in[8];
  const float* bhh1  = (const float*)d_in[9];
  const float* ln_g  = (const float*)d_in[10];
  const float* ln_b  = (const float*)d_in[11];
  const float* projW = (const float*)d_in[12];
  const float* projb = (const float*)d_in[13];

  hipFuncSetAttribute((const void*)lstm_persist,
                      hipFuncAttributeMaxDynamicSharedMemorySize, SCAN_LDS);

  // footprint: xpA0+xpA1+xpB (3*T*524288) + iobuf (T*131072) + FIXED
  const size_t FIXED = 2138112;   // weights 1.84M + hs1 256K + barriers 32K
  int T = 64;
  while (T > 4 && FIXED + (size_t)T * 1703936 > ws_size) T >>= 1;
  int nch = NS / T;

  char* ws = (char*)d_ws;
  u16*   xpA0  = (u16*)(ws);
  u16*   xpA1  = (u16*)(ws + (size_t)T * 524288);
  u16*   xpB   = (u16*)(ws + (size_t)T * 1048576);
  u16*   iobuf = (u16*)(ws + (size_t)T * 1572864);   // e (prologue) / h1 chunk
  char*  wbase = ws + (size_t)T * 1703936;
  u16*   wih0b = (u16*)(wbase);
  u16*   whh0b = (u16*)(wbase + 262144);
  u16*   wih1b = (u16*)(wbase + 786432);
  u16*   whh1b = (u16*)(wbase + 1310720);
  float* bc0   = (float*)(wbase + 1835008);
  float* bc1   = (float*)(wbase + 1839104);
  float* hs1   = (float*)(wbase + 1843200);
  u32*   bar   = (u32*)(wbase + 2105344);            // 32KB counters

  zero_flags<<<32, 256, 0, stream>>>(bar, 8192);
  prep_weights<<<256, 256, 0, stream>>>(Wih0, Whh0, bih0, bhh0, Wih1, Whh1, bih1, bhh1,
                                        wih0b, whh0b, wih1b, whh1b, bc0, bc1);
  // prologue: xpA0 for L0 chunk 0
  embed_chunk<<<T * 32, 256, 0, stream>>>(x, emb, iobuf, 0);
  xp_gemm<NE><<<T * 16, 256, 0, stream>>>(iobuf, wih0b, bc0, xpA0);

  lstm_persist<<<NWG, 512, SCAN_LDS, stream>>>(
      x, emb, wih0b, bc0, whh0b, whh1b, wih1b, bc1,
      xpA0, xpA1, xpB, iobuf, hs1, bar, T, nch);

  ln_proj<<<NB, 256, 0, stream>>>(hs1, ln_g, ln_b, projW, projb, (float*)d_out);
}

// Round 16
// 1985.767 us; speedup vs baseline: 2.1941x; 2.1941x over previous
//
#include <hip/hip_runtime.h>
#include <hip/hip_bf16.h>

// ---------------------------------------------------------------------------
// 2-layer LSTM (B=256,S=512,E=128,H=256) + LayerNorm + projection.
// Round 15: R14 persistent pipeline + FIXED grid barrier. R14's gbar spun on
// an ACQUIRE agent-scope load -> buffer_inv (L2 invalidate) on EVERY poll
// from 224 WGs => ~170us/barrier + destroyed L2 locality (4357us total).
// Fix: release fence ONCE + RELAXED add; spin on RELAXED loads (no inv);
// acquire fence ONCE after exit. Everything else verbatim R14 (passed).
//   phase 2s  : scan WGs chunk s (L0) / s-1 (L1), weights persistent;
//               helpers embed+gemmA(s+1) -> xpA[(s+1)&1]
//   barrier
//   phase 2s+1: helpers gemmB h1(s) -> xpB
//   barrier
// ---------------------------------------------------------------------------

typedef unsigned short u16;
typedef unsigned int   u32;
using short8 = __attribute__((ext_vector_type(8))) short;
using f32x4  = __attribute__((ext_vector_type(4))) float;

#define NB 256
#define NS 512
#define NE 128
#define NH 256
#define NG 1024  // 4*H

#define WLDS_FRAGS 18
#define HOFF 147456
#define SCAN_LDS (HOFF + 2 * 16 * NH * 2)   // 163840 = 160 KiB

#define NSCAN 32
#define NHELP 192
#define NWG   (NSCAN + NHELP)

#define L2E     1.4426950408889634f
#define TWO_L2E 2.8853900817779268f

__device__ __forceinline__ u16 f2b(float x) {
  __hip_bfloat16 h = __float2bfloat16(x);
  return __builtin_bit_cast(u16, h);
}
__device__ __forceinline__ float b2f(u16 u) {
  return __builtin_bit_cast(float, (u32)u << 16);
}
__device__ __forceinline__ float ex2(float x)  { return __builtin_amdgcn_exp2f(x); }
__device__ __forceinline__ float ex2n(float x) { return __builtin_amdgcn_exp2f(-x); }
__device__ __forceinline__ float rcpa(float x) { return __builtin_amdgcn_rcpf(x); }

// ---- grid barrier: release-fence once, RELAXED add, RELAXED spin (no
// per-poll L2 invalidate), acquire-fence once after exit ----
__device__ __forceinline__ void gbar(u32* bar, int ph, int tid) {
  __syncthreads();                     // all WG work done, LDS/global stores issued
  if (tid == 0) {
    __threadfence();                   // release: publish our stores (wbL2 once)
    __hip_atomic_fetch_add(bar + ph * 16, 1u, __ATOMIC_RELAXED, __HIP_MEMORY_SCOPE_AGENT);
    while (__hip_atomic_load(bar + ph * 16, __ATOMIC_RELAXED, __HIP_MEMORY_SCOPE_AGENT) < (u32)NWG)
      __builtin_amdgcn_s_sleep(32);
    __threadfence();                   // acquire: invalidate stale lines (once)
  }
  __syncthreads();                     // whole WG proceeds after fresh state
}

// ---------------- prep: fp32 weights -> bf16 (exp2-prescaled), biases ------
__global__ __launch_bounds__(256) void prep_weights(
    const float* Wih0, const float* Whh0, const float* bih0, const float* bhh0,
    const float* Wih1, const float* Whh1, const float* bih1, const float* bhh1,
    u16* wih0b, u16* whh0b, u16* wih1b, u16* whh1b, float* bc0, float* bc1) {
  int stride = gridDim.x * blockDim.x;
  int tid = blockIdx.x * blockDim.x + threadIdx.x;
  for (int i = tid; i < NG * NE; i += stride) {
    float s = (((i >> 7) >> 8) == 2) ? TWO_L2E : L2E;
    wih0b[i] = f2b(Wih0[i] * s);
  }
  for (int i = tid; i < NG * NH; i += stride) {
    float s = (((i >> 8) >> 8) == 2) ? TWO_L2E : L2E;
    whh0b[i] = f2b(Whh0[i] * s);
    wih1b[i] = f2b(Wih1[i] * s);
    whh1b[i] = f2b(Whh1[i] * s);
  }
  for (int i = tid; i < NG; i += stride) {
    float s = ((i >> 8) == 2) ? TWO_L2E : L2E;
    bc0[i] = (bih0[i] + bhh0[i]) * s;
    bc1[i] = (bih1[i] + bhh1[i]) * s;
  }
}

__global__ __launch_bounds__(256) void zero_flags(u32* f, int n) {
  int i = blockIdx.x * 256 + threadIdx.x;
  if (i < n) f[i] = 0;
}

// ---------------- embedding gather (prologue chunk 0 only) -----------------
__global__ __launch_bounds__(256) void embed_chunk(const int* __restrict__ x,
                                                   const float* __restrict__ emb,
                                                   u16* __restrict__ ebuf, int t0) {
  int gid = blockIdx.x * 256 + threadIdx.x;
  int d4 = gid & 31;
  int sb = gid >> 5;
  int b  = sb & (NB - 1);
  int sl = sb >> 8;
  int tok = x[b * NS + (t0 + sl)];
  float4 v = make_float4(0.f, 0.f, 0.f, 0.f);
  if (tok != 0) v = *(const float4*)(emb + (size_t)tok * NE + d4 * 4);
  ushort4 o;
  o.x = f2b(v.x); o.y = f2b(v.y); o.z = f2b(v.z); o.w = f2b(v.w);
  *(ushort4*)(ebuf + (size_t)sb * NE + d4 * 4) = o;
}

// ---------------- xp GEMM (prologue chunk 0 only) --------------------------
template <int K>
__global__ __launch_bounds__(256) void xp_gemm(const u16* __restrict__ A,
                                               const u16* __restrict__ W,
                                               const float* __restrict__ bias,
                                               u16* __restrict__ Cout) {
  __shared__ __align__(16) char lds[2 * 128 * 80];
  char* Asm = lds;
  char* Bsm = lds + 128 * 80;
  int tid = threadIdx.x;
  int w = tid >> 6, l = tid & 63;
  int hi = l >> 4, lo = l & 15;
  int mblk = blockIdx.x >> 3, nblk = blockIdx.x & 7;
  size_t arow0 = (size_t)mblk * 128;
  int g0 = nblk * 128;
  int wm = (w >> 1) * 64, wn = (w & 1) * 64;
  f32x4 acc[4][4] = {};
  int r = tid >> 1, cp = tid & 1;

  for (int k0 = 0; k0 < K; k0 += 32) {
    int4 a0 = *(const int4*)(A + (arow0 + r) * K + k0 + cp * 16);
    int4 a1 = *(const int4*)(A + (arow0 + r) * K + k0 + cp * 16 + 8);
    int4 b0 = *(const int4*)(W + (size_t)(g0 + r) * K + k0 + cp * 16);
    int4 b1 = *(const int4*)(W + (size_t)(g0 + r) * K + k0 + cp * 16 + 8);
    *(int4*)(Asm + r * 80 + cp * 32)      = a0;
    *(int4*)(Asm + r * 80 + cp * 32 + 16) = a1;
    *(int4*)(Bsm + r * 80 + cp * 32)      = b0;
    *(int4*)(Bsm + r * 80 + cp * 32 + 16) = b1;
    __syncthreads();
    short8 af[4], bfr[4];
#pragma unroll
    for (int mt = 0; mt < 4; ++mt)
      af[mt] = *(const short8*)(Asm + (wm + mt * 16 + lo) * 80 + hi * 16);
#pragma unroll
    for (int nt = 0; nt < 4; ++nt)
      bfr[nt] = *(const short8*)(Bsm + (wn + nt * 16 + lo) * 80 + hi * 16);
#pragma unroll
    for (int mt = 0; mt < 4; ++mt)
#pragma unroll
      for (int nt = 0; nt < 4; ++nt)
        acc[mt][nt] = __builtin_amdgcn_mfma_f32_16x16x32_bf16(af[mt], bfr[nt], acc[mt][nt], 0, 0, 0);
    __syncthreads();
  }
#pragma unroll
  for (int nt = 0; nt < 4; ++nt) {
    int gc = g0 + wn + nt * 16 + lo;
    float bv = bias[gc];
    int ws_ = (gc >> 4) & 7, mts = gc >> 7, his = (gc >> 2) & 3, rs = gc & 3;
    size_t gbase = ((size_t)(ws_ * 8 + mts) << 8) + (size_t)(his * 16) * 4 + rs;
#pragma unroll
    for (int mt = 0; mt < 4; ++mt) {
      size_t row = arow0 + wm + mt * 16 + hi * 4;
#pragma unroll
      for (int rr = 0; rr < 4; ++rr) {
        size_t rw = row + rr;
        int t = (int)(rw >> 8), ba = (int)(rw & 255);
        size_t e = ((size_t)(t * 16 + (ba >> 4)) << 14) + gbase + (size_t)(ba & 15) * 4;
        Cout[e] = f2b(acc[mt][nt][rr] + bv);
      }
    }
  }
}

// ---------------- persistent pipeline kernel -------------------------------
__global__ __launch_bounds__(512, 2)
void lstm_persist(const int* __restrict__ x, const float* __restrict__ emb,
                  const u16* __restrict__ wih0b, const float* __restrict__ bc0,
                  const u16* __restrict__ whh0b, const u16* __restrict__ whh1b,
                  const u16* __restrict__ wih1b, const float* __restrict__ bc1,
                  u16* __restrict__ xpA0, u16* __restrict__ xpA1,
                  u16* __restrict__ xpB, u16* __restrict__ iobuf,
                  float* __restrict__ hs1, u32* __restrict__ bar,
                  int T, int nch) {
  extern __shared__ __align__(16) char smem[];
  int bid = blockIdx.x;
  int tid = threadIdx.x;

  if (bid >= NSCAN) {
    // ================= helper WGs: role C (embed+gemmA) then gemmB =========
    int team = tid >> 8, tt = tid & 255;
    char* Asm = smem + team * 40960;
    char* Bsm = Asm + 20480;
    int wq = tt >> 6, lq = tt & 63;
    int hiq = lq >> 4, loq = lq & 15;
    int wm = (wq >> 1) * 64, wn = (wq & 1) * 64;
    int r = tt >> 1, cp = tt & 1;
    int tg = (bid - NSCAN) * 2 + team;
    const int stride = NHELP * 2;
    int njobs = T * 16;
    int nIt = (njobs + stride - 1) / stride;

    for (int s = 0; s <= nch; ++s) {
      // ---- phase 2s: role C -> xpA[(s+1)&1] for chunk s+1 ----
      if (s + 1 < nch) {
        u16* xpC = ((s + 1) & 1) ? xpA1 : xpA0;
        int t0c = (s + 1) * T;
        for (int it = 0; it < nIt; ++it) {
          int j = tg + it * stride;
          bool act = j < njobs;
          int jj = act ? j : 0;
          int mblk = jj >> 3, nblk = jj & 7;
          size_t arow0 = (size_t)mblk * 128;
          int g0 = nblk * 128;
          f32x4 acc[4][4] = {};
          int rw = (int)(arow0 + r);
          int sl = rw >> 8, ba = rw & 255;
          int tok = x[ba * NS + t0c + sl];
          const float* erow = emb + (size_t)tok * NE;
          for (int k0 = 0; k0 < NE; k0 += 32) {
            const float* src = erow + k0 + cp * 16;
            u32 pk[8];
#pragma unroll
            for (int q = 0; q < 8; ++q) {
              float a = src[2 * q], b = src[2 * q + 1];
              if (tok == 0) { a = 0.0f; b = 0.0f; }
              pk[q] = (u32)f2b(a) | ((u32)f2b(b) << 16);
            }
            *(int4*)(Asm + r * 80 + cp * 32)      = *(int4*)&pk[0];
            *(int4*)(Asm + r * 80 + cp * 32 + 16) = *(int4*)&pk[4];
            int4 b0 = *(const int4*)(wih0b + (size_t)(g0 + r) * NE + k0 + cp * 16);
            int4 b1 = *(const int4*)(wih0b + (size_t)(g0 + r) * NE + k0 + cp * 16 + 8);
            *(int4*)(Bsm + r * 80 + cp * 32)      = b0;
            *(int4*)(Bsm + r * 80 + cp * 32 + 16) = b1;
            __syncthreads();
            short8 af[4], bfr[4];
#pragma unroll
            for (int mt = 0; mt < 4; ++mt)
              af[mt] = *(const short8*)(Asm + (wm + mt * 16 + loq) * 80 + hiq * 16);
#pragma unroll
            for (int nt = 0; nt < 4; ++nt)
              bfr[nt] = *(const short8*)(Bsm + (wn + nt * 16 + loq) * 80 + hiq * 16);
#pragma unroll
            for (int mt = 0; mt < 4; ++mt)
#pragma unroll
              for (int nt = 0; nt < 4; ++nt)
                acc[mt][nt] = __builtin_amdgcn_mfma_f32_16x16x32_bf16(af[mt], bfr[nt], acc[mt][nt], 0, 0, 0);
            __syncthreads();
          }
          if (act) {
#pragma unroll
            for (int nt = 0; nt < 4; ++nt) {
              int gc = g0 + wn + nt * 16 + loq;
              float bv = bc0[gc];
              int ws_ = (gc >> 4) & 7, mts = gc >> 7, his = (gc >> 2) & 3, rs = gc & 3;
              size_t gbase = ((size_t)(ws_ * 8 + mts) << 8) + (size_t)(his * 16) * 4 + rs;
#pragma unroll
              for (int mt = 0; mt < 4; ++mt) {
                size_t row = arow0 + wm + mt * 16 + hiq * 4;
#pragma unroll
                for (int rr = 0; rr < 4; ++rr) {
                  size_t rw2 = row + rr;
                  int t = (int)(rw2 >> 8), ba2 = (int)(rw2 & 255);
                  size_t e = ((size_t)(t * 16 + (ba2 >> 4)) << 14) + gbase + (size_t)(ba2 & 15) * 4;
                  xpC[e] = f2b(acc[mt][nt][rr] + bv);
                }
              }
            }
          }
        }
      }
      gbar(bar, 2 * s, tid);
      // ---- phase 2s+1: gemmB  h1(s)(iobuf) -> xpB ----
      if (s < nch) {
        for (int it = 0; it < nIt; ++it) {
          int j = tg + it * stride;
          bool act = j < njobs;
          int jj = act ? j : 0;
          int mblk = jj >> 3, nblk = jj & 7;
          size_t arow0 = (size_t)mblk * 128;
          int g0 = nblk * 128;
          f32x4 acc[4][4] = {};
          for (int k0 = 0; k0 < NH; k0 += 32) {
            int4 a0 = *(const int4*)(iobuf + (arow0 + r) * NH + k0 + cp * 16);
            int4 a1 = *(const int4*)(iobuf + (arow0 + r) * NH + k0 + cp * 16 + 8);
            int4 b0 = *(const int4*)(wih1b + (size_t)(g0 + r) * NH + k0 + cp * 16);
            int4 b1 = *(const int4*)(wih1b + (size_t)(g0 + r) * NH + k0 + cp * 16 + 8);
            *(int4*)(Asm + r * 80 + cp * 32)      = a0;
            *(int4*)(Asm + r * 80 + cp * 32 + 16) = a1;
            *(int4*)(Bsm + r * 80 + cp * 32)      = b0;
            *(int4*)(Bsm + r * 80 + cp * 32 + 16) = b1;
            __syncthreads();
            short8 af[4], bfr[4];
#pragma unroll
            for (int mt = 0; mt < 4; ++mt)
              af[mt] = *(const short8*)(Asm + (wm + mt * 16 + loq) * 80 + hiq * 16);
#pragma unroll
            for (int nt = 0; nt < 4; ++nt)
              bfr[nt] = *(const short8*)(Bsm + (wn + nt * 16 + loq) * 80 + hiq * 16);
#pragma unroll
            for (int mt = 0; mt < 4; ++mt)
#pragma unroll
              for (int nt = 0; nt < 4; ++nt)
                acc[mt][nt] = __builtin_amdgcn_mfma_f32_16x16x32_bf16(af[mt], bfr[nt], acc[mt][nt], 0, 0, 0);
            __syncthreads();
          }
          if (act) {
#pragma unroll
            for (int nt = 0; nt < 4; ++nt) {
              int gc = g0 + wn + nt * 16 + loq;
              float bv = bc1[gc];
              int ws_ = (gc >> 4) & 7, mts = gc >> 7, his = (gc >> 2) & 3, rs = gc & 3;
              size_t gbase = ((size_t)(ws_ * 8 + mts) << 8) + (size_t)(his * 16) * 4 + rs;
#pragma unroll
              for (int mt = 0; mt < 4; ++mt) {
                size_t row = arow0 + wm + mt * 16 + hiq * 4;
#pragma unroll
                for (int rr = 0; rr < 4; ++rr) {
                  size_t rw2 = row + rr;
                  int t = (int)(rw2 >> 8), ba2 = (int)(rw2 & 255);
                  size_t e = ((size_t)(t * 16 + (ba2 >> 4)) << 14) + gbase + (size_t)(ba2 & 15) * 4;
                  xpB[e] = f2b(acc[mt][nt][rr] + bv);
                }
              }
            }
          }
        }
      }
      gbar(bar, 2 * s + 1, tid);
    }
    return;
  }

  // ================= scan WGs: role A (L0) / role B (L1), persistent =======
  int roleB = bid >> 4;
  int bgi = bid & 15;
  int bg = bgi * 16;
  const u16* whh = roleB ? whh1b : whh0b;

  int w = tid >> 6, l = tid & 63;
  int hi = l >> 4, lo = l & 15;

  // ---- load Whh into regs + LDS (ONCE for the whole sequence) ----
  int wbase = w * (WLDS_FRAGS * 1024) + l * 16;
  short8 wfv[8][5];
  short8 wfv2[6];
#pragma unroll
  for (int mt = 0; mt < 8; ++mt) {
#pragma unroll
    for (int p = 0; p < 8; ++p) {
      const u16* src = whh + (size_t)(16 * (w + 8 * mt) + lo) * NH + p * 32 + hi * 8;
      short8 v = *(const short8*)src;
      if (p < 2)                 *(short8*)(smem + wbase + (p * 8 + mt) * 1024) = v;
      else if (p == 2 && mt < 2) *(short8*)(smem + wbase + (16 + mt) * 1024) = v;
      else if (p == 2)           wfv2[mt - 2] = v;
      else                       wfv[mt][p - 3] = v;
    }
  }
  // ---- init h = 0 (LDS buffer 0), c = 0 (ONCE) ----
  float c[2][4];
  for (int i = tid; i < 16 * NH / 2; i += 512) ((u32*)(smem + HOFF))[i] = 0;
#pragma unroll
  for (int g = 0; g < 2; ++g)
#pragma unroll
    for (int r = 0; r < 4; ++r) c[g][r] = 0.0f;
  __syncthreads();

  // ---- step-invariant offsets ----
  int rdoff = (l ^ ((l >> 3) & 7)) * 16;
  int wroff[2];
#pragma unroll
  for (int g = 0; g < 2; ++g) {
    int xx = (2 * (w & 1) + (hi >> 1)) * 16 + lo;
    wroff[g] = (4 * g + (w >> 1)) * 1024 + (xx ^ ((xx >> 3) & 7)) * 16 + 8 * (hi & 1);
  }
  int bq = tid >> 5, kc = tid & 31;
  int xw = (kc & 3) * 16 + bq;
  int wboff = (kc >> 2) * 1024 + (xw ^ ((xw >> 3) & 7)) * 16;
  size_t wb_glob = (size_t)(bg + bq) * NH + kc * 8;

  f32x4 acc[8];
  for (int s = 0; s <= nch; ++s) {
    bool act = roleB ? (s >= 1) : (s < nch);
    if (act) {
      int mc = roleB ? (s - 1) : s;
      const u16* xp = roleB ? xpB : ((mc & 1) ? xpA1 : xpA0);
      u16* hout = roleB ? (u16*)0 : iobuf;
      const u16* xpp = xp + ((size_t)(bgi * 8 + w) * 2048) + (size_t)l * 4;
      ushort4 xq[8];
#pragma unroll
      for (int mt = 0; mt < 8; ++mt) xq[mt] = *(const ushort4*)(xpp + mt * 256);

      for (int t = 0; t < T; ++t) {
        int rbase = HOFF + ((t & 1) << 13);
        int wbbase = HOFF + ((~t & 1) << 13);
#pragma unroll
        for (int mt = 0; mt < 8; ++mt) {
          f32x4 a;
          a[0] = b2f(xq[mt].x); a[1] = b2f(xq[mt].y);
          a[2] = b2f(xq[mt].z); a[3] = b2f(xq[mt].w);
          acc[mt] = a;
        }
        xpp += 262144;   // next t (final overrun: adjacent ws buffer, discarded)
#pragma unroll
        for (int mt = 0; mt < 8; ++mt) xq[mt] = *(const ushort4*)(xpp + mt * 256);
#pragma unroll
        for (int p = 0; p < 8; ++p) {
          short8 bf = *(const short8*)(smem + rbase + rdoff + p * 1024);
#pragma unroll
          for (int mt = 0; mt < 8; ++mt) {
            short8 af;
            if (p < 2)                 af = *(const short8*)(smem + wbase + (p * 8 + mt) * 1024);
            else if (p == 2 && mt < 2) af = *(const short8*)(smem + wbase + (16 + mt) * 1024);
            else if (p == 2)           af = wfv2[mt - 2];
            else                       af = wfv[mt][p - 3];
            acc[mt] = __builtin_amdgcn_mfma_f32_16x16x32_bf16(af, bf, acc[mt], 0, 0, 0);
          }
        }
#pragma unroll
        for (int g = 0; g < 2; ++g) {
          float hv[4];
#pragma unroll
          for (int r = 0; r < 4; ++r) {
            float iv = rcpa(1.0f + ex2n(acc[g][r]));
            float fv = rcpa(1.0f + ex2n(acc[2 + g][r]));
            float gv = 1.0f - 2.0f * rcpa(ex2(acc[4 + g][r]) + 1.0f);
            float ov = rcpa(1.0f + ex2n(acc[6 + g][r]));
            float cc = fv * c[g][r] + iv * gv;
            c[g][r] = cc;
            float th = 1.0f - 2.0f * rcpa(ex2(cc * TWO_L2E) + 1.0f);
            hv[r] = ov * th;
          }
          u32 d0, d1;
          asm("v_cvt_pk_bf16_f32 %0, %1, %2" : "=v"(d0) : "v"(hv[0]), "v"(hv[1]));
          asm("v_cvt_pk_bf16_f32 %0, %1, %2" : "=v"(d1) : "v"(hv[2]), "v"(hv[3]));
          uint2 hw; hw.x = d0; hw.y = d1;
          *(uint2*)(smem + wbbase + wroff[g]) = hw;
        }
        __syncthreads();
        if (hout) {
          int4 hv4 = *(const int4*)(smem + wbbase + wboff);
          *(int4*)(hout + wb_glob + ((size_t)t << 16)) = hv4;
        }
      }
    }
    gbar(bar, 2 * s, tid);
    gbar(bar, 2 * s + 1, tid);
  }

  // ---- role B: final h -> hs1 for ln_proj (T even => final h in buf 0) ----
  if (roleB) {
#pragma unroll
    for (int g = 0; g < 2; ++g) {
      ushort4 hv4 = *(const ushort4*)(smem + HOFF + wroff[g]);
      int j = 16 * w + 128 * g + 4 * hi;
      u16 hb[4] = {hv4.x, hv4.y, hv4.z, hv4.w};
#pragma unroll
      for (int r = 0; r < 4; ++r)
        hs1[(size_t)(bg + lo) * NH + j + r] = b2f(hb[r]);
    }
  }
}

// ---------------- LayerNorm + projection -----------------------------------
__global__ __launch_bounds__(256) void ln_proj(const float* __restrict__ hn,
                                               const float* __restrict__ lng,
                                               const float* __restrict__ lnb,
                                               const float* __restrict__ pW,
                                               const float* __restrict__ pb,
                                               float* __restrict__ out) {
  __shared__ __align__(16) float nbuf[NH];
  __shared__ float red[8];
  int b = blockIdx.x, tid = threadIdx.x;
  float v = hn[(size_t)b * NH + tid];
  float s = v, s2 = v * v;
#pragma unroll
  for (int o = 32; o > 0; o >>= 1) {
    s  += __shfl_down(s, o);
    s2 += __shfl_down(s2, o);
  }
  if ((tid & 63) == 0) { red[tid >> 6] = s; red[4 + (tid >> 6)] = s2; }
  __syncthreads();
  if (tid == 0) {
    red[0] = red[0] + red[1] + red[2] + red[3];
    red[4] = red[4] + red[5] + red[6] + red[7];
  }
  __syncthreads();
  float mean = red[0] * (1.0f / NH);
  float var  = red[4] * (1.0f / NH) - mean * mean;
  float rs = rsqrtf(var + 1e-5f);
  nbuf[tid] = (v - mean) * rs * lng[tid] + lnb[tid];
  __syncthreads();
  if (tid < NE) {
    float a = pb[tid];
    const float* wr = pW + (size_t)tid * NH;
#pragma unroll 4
    for (int j = 0; j < NH; ++j) a = fmaf(nbuf[j], wr[j], a);
    out[(size_t)b * NE + tid] = a;
  }
}

// ---------------------------------------------------------------------------
extern "C" void kernel_launch(void* const* d_in, const int* in_sizes, int n_in,
                              void* d_out, int out_size, void* d_ws, size_t ws_size,
                              hipStream_t stream) {
  const int*   x     = (const int*)d_in[0];
  const float* emb   = (const float*)d_in[1];
  const float* Wih0  = (const float*)d_in[2];
  const float* Whh0  = (const float*)d_in[3];
  const float* bih0  = (const float*)d_in[4];
  const float* bhh0  = (const float*)d_in[5];
  const float* Wih1  = (const float*)d_in[6];
  const float* Whh1  = (const float*)d_in[7];
  const float* bih1  = (const float*)d_in[8];
  const float* bhh1  = (const float*)d_in[9];
  const float* ln_g  = (const float*)d_in[10];
  const float* ln_b  = (const float*)d_in[11];
  const float* projW = (const float*)d_in[12];
  const float* projb = (const float*)d_in[13];

  hipFuncSetAttribute((const void*)lstm_persist,
                      hipFuncAttributeMaxDynamicSharedMemorySize, SCAN_LDS);

  // footprint: xpA0+xpA1+xpB (3*T*524288) + iobuf (T*131072) + FIXED
  const size_t FIXED = 2138112;   // weights 1.84M + hs1 256K + barriers 32K
  int T = 64;
  while (T > 4 && FIXED + (size_t)T * 1703936 > ws_size) T >>= 1;
  int nch = NS / T;

  char* ws = (char*)d_ws;
  u16*   xpA0  = (u16*)(ws);
  u16*   xpA1  = (u16*)(ws + (size_t)T * 524288);
  u16*   xpB   = (u16*)(ws + (size_t)T * 1048576);
  u16*   iobuf = (u16*)(ws + (size_t)T * 1572864);   // e (prologue) / h1 chunk
  char*  wbase = ws + (size_t)T * 1703936;
  u16*   wih0b = (u16*)(wbase);
  u16*   whh0b = (u16*)(wbase + 262144);
  u16*   wih1b = (u16*)(wbase + 786432);
  u16*   whh1b = (u16*)(wbase + 1310720);
  float* bc0   = (float*)(wbase + 1835008);
  float* bc1   = (float*)(wbase + 1839104);
  float* hs1   = (float*)(wbase + 1843200);
  u32*   bar   = (u32*)(wbase + 2105344);            // 32KB counters

  zero_flags<<<32, 256, 0, stream>>>(bar, 8192);
  prep_weights<<<256, 256, 0, stream>>>(Wih0, Whh0, bih0, bhh0, Wih1, Whh1, bih1, bhh1,
                                        wih0b, whh0b, wih1b, whh1b, bc0, bc1);
  // prologue: xpA0 for L0 chunk 0
  embed_chunk<<<T * 32, 256, 0, stream>>>(x, emb, iobuf, 0);
  xp_gemm<NE><<<T * 16, 256, 0, stream>>>(iobuf, wih0b, bc0, xpA0);

  lstm_persist<<<NWG, 512, SCAN_LDS, stream>>>(
      x, emb, wih0b, bc0, whh0b, whh1b, wih1b, bc1,
      xpA0, xpA1, xpB, iobuf, hs1, bar, T, nch);

  ln_proj<<<NB, 256, 0, stream>>>(hs1, ln_g, ln_b, projW, projb, (float*)d_out);
}

// Round 17
// 1392.067 us; speedup vs baseline: 3.1298x; 1.4265x over previous
//
#include <hip/hip_runtime.h>
#include <hip/hip_bf16.h>

// ---------------------------------------------------------------------------
// 2-layer LSTM (B=256,S=512,E=128,H=256) + LayerNorm + projection.
// Round 16: persistent pipeline, DEPTH-3 schedule (one barrier/stage) +
// tree barrier (8 sub-counters, wave-poll) + 128 WGs (32 scan + 96 helper).
// Stage s (s = 0..nch+1), all roles concurrent, ONE barrier at stage end:
//   scanA : L0 chunk s       reads xpA[s&1],  writes h1 -> io[s&1]
//   scanB : L1 chunk s-2     reads xpB[s&1]   (= parity (s-2)&1)
//   roleC : chunk s+1 embed+gemmA -> xpA[(s+1)&1]
//   gemmB : chunk s-1 h1 (io[(s-1)&1]) -> xpB[(s-1)&1]
// Every producer->consumer edge crosses exactly one barrier (parity dbuf).
// Scan math verbatim R9-R15 (passed, absmax 0.0156). Barriers: monotonic
// tree counters, R15-validated fence placement.
// ---------------------------------------------------------------------------

typedef unsigned short u16;
typedef unsigned int   u32;
using short8 = __attribute__((ext_vector_type(8))) short;
using f32x4  = __attribute__((ext_vector_type(4))) float;

#define NB 256
#define NS 512
#define NE 128
#define NH 256
#define NG 1024  // 4*H

#define WLDS_FRAGS 18
#define HOFF 147456
#define SCAN_LDS (HOFF + 2 * 16 * NH * 2)   // 163840 = 160 KiB

#define NSCAN 32
#define NHELP 96
#define NWG   (NSCAN + NHELP)   // 128 <= 256 CUs @ 160KB LDS: co-resident

#define L2E     1.4426950408889634f
#define TWO_L2E 2.8853900817779268f

__device__ __forceinline__ u16 f2b(float x) {
  __hip_bfloat16 h = __float2bfloat16(x);
  return __builtin_bit_cast(u16, h);
}
__device__ __forceinline__ float b2f(u16 u) {
  return __builtin_bit_cast(float, (u32)u << 16);
}
__device__ __forceinline__ float ex2(float x)  { return __builtin_amdgcn_exp2f(x); }
__device__ __forceinline__ float ex2n(float x) { return __builtin_amdgcn_exp2f(-x); }
__device__ __forceinline__ float rcpa(float x) { return __builtin_amdgcn_rcpf(x); }

// ---- tree grid barrier: 8 sub-counters (128B apart), monotonic targets.
// Arrival: 1 relaxed RMW on line (bid&7). Detect: wave0 sums all 8.
// Fence placement identical to R15 (validated): release fence before add,
// acquire fence after detection, both by tid0.
__device__ __forceinline__ void gbar(u32* bar, int ph, int tid, int bid) {
  __syncthreads();
  if (tid == 0) {
    __threadfence();                   // release: publish stores
    __hip_atomic_fetch_add(bar + (bid & 7) * 32, 1u,
                           __ATOMIC_RELAXED, __HIP_MEMORY_SCOPE_AGENT);
  }
  if (tid < 64) {
    u32 target = (u32)NWG * (u32)(ph + 1);
    for (;;) {
      u32 v = 0;
      if (tid < 8)
        v = __hip_atomic_load(bar + tid * 32, __ATOMIC_RELAXED,
                              __HIP_MEMORY_SCOPE_AGENT);
      v += __shfl_down(v, 4);
      v += __shfl_down(v, 2);
      v += __shfl_down(v, 1);
      v = __shfl(v, 0);
      if (v >= target) break;
      __builtin_amdgcn_s_sleep(8);
    }
  }
  __syncthreads();
  if (tid == 0) __threadfence();       // acquire: refresh caches (once)
  __syncthreads();
}

// ---------------- prep: fp32 weights -> bf16 (exp2-prescaled), biases ------
__global__ __launch_bounds__(256) void prep_weights(
    const float* Wih0, const float* Whh0, const float* bih0, const float* bhh0,
    const float* Wih1, const float* Whh1, const float* bih1, const float* bhh1,
    u16* wih0b, u16* whh0b, u16* wih1b, u16* whh1b, float* bc0, float* bc1) {
  int stride = gridDim.x * blockDim.x;
  int tid = blockIdx.x * blockDim.x + threadIdx.x;
  for (int i = tid; i < NG * NE; i += stride) {
    float s = (((i >> 7) >> 8) == 2) ? TWO_L2E : L2E;
    wih0b[i] = f2b(Wih0[i] * s);
  }
  for (int i = tid; i < NG * NH; i += stride) {
    float s = (((i >> 8) >> 8) == 2) ? TWO_L2E : L2E;
    whh0b[i] = f2b(Whh0[i] * s);
    wih1b[i] = f2b(Wih1[i] * s);
    whh1b[i] = f2b(Whh1[i] * s);
  }
  for (int i = tid; i < NG; i += stride) {
    float s = ((i >> 8) == 2) ? TWO_L2E : L2E;
    bc0[i] = (bih0[i] + bhh0[i]) * s;
    bc1[i] = (bih1[i] + bhh1[i]) * s;
  }
}

__global__ __launch_bounds__(256) void zero_flags(u32* f, int n) {
  int i = blockIdx.x * 256 + threadIdx.x;
  if (i < n) f[i] = 0;
}

// ---------------- embedding gather (prologue chunk 0 only) -----------------
__global__ __launch_bounds__(256) void embed_chunk(const int* __restrict__ x,
                                                   const float* __restrict__ emb,
                                                   u16* __restrict__ ebuf, int t0) {
  int gid = blockIdx.x * 256 + threadIdx.x;
  int d4 = gid & 31;
  int sb = gid >> 5;
  int b  = sb & (NB - 1);
  int sl = sb >> 8;
  int tok = x[b * NS + (t0 + sl)];
  float4 v = make_float4(0.f, 0.f, 0.f, 0.f);
  if (tok != 0) v = *(const float4*)(emb + (size_t)tok * NE + d4 * 4);
  ushort4 o;
  o.x = f2b(v.x); o.y = f2b(v.y); o.z = f2b(v.z); o.w = f2b(v.w);
  *(ushort4*)(ebuf + (size_t)sb * NE + d4 * 4) = o;
}

// ---------------- xp GEMM (prologue chunk 0 only) --------------------------
template <int K>
__global__ __launch_bounds__(256) void xp_gemm(const u16* __restrict__ A,
                                               const u16* __restrict__ W,
                                               const float* __restrict__ bias,
                                               u16* __restrict__ Cout) {
  __shared__ __align__(16) char lds[2 * 128 * 80];
  char* Asm = lds;
  char* Bsm = lds + 128 * 80;
  int tid = threadIdx.x;
  int w = tid >> 6, l = tid & 63;
  int hi = l >> 4, lo = l & 15;
  int mblk = blockIdx.x >> 3, nblk = blockIdx.x & 7;
  size_t arow0 = (size_t)mblk * 128;
  int g0 = nblk * 128;
  int wm = (w >> 1) * 64, wn = (w & 1) * 64;
  f32x4 acc[4][4] = {};
  int r = tid >> 1, cp = tid & 1;

  for (int k0 = 0; k0 < K; k0 += 32) {
    int4 a0 = *(const int4*)(A + (arow0 + r) * K + k0 + cp * 16);
    int4 a1 = *(const int4*)(A + (arow0 + r) * K + k0 + cp * 16 + 8);
    int4 b0 = *(const int4*)(W + (size_t)(g0 + r) * K + k0 + cp * 16);
    int4 b1 = *(const int4*)(W + (size_t)(g0 + r) * K + k0 + cp * 16 + 8);
    *(int4*)(Asm + r * 80 + cp * 32)      = a0;
    *(int4*)(Asm + r * 80 + cp * 32 + 16) = a1;
    *(int4*)(Bsm + r * 80 + cp * 32)      = b0;
    *(int4*)(Bsm + r * 80 + cp * 32 + 16) = b1;
    __syncthreads();
    short8 af[4], bfr[4];
#pragma unroll
    for (int mt = 0; mt < 4; ++mt)
      af[mt] = *(const short8*)(Asm + (wm + mt * 16 + lo) * 80 + hi * 16);
#pragma unroll
    for (int nt = 0; nt < 4; ++nt)
      bfr[nt] = *(const short8*)(Bsm + (wn + nt * 16 + lo) * 80 + hi * 16);
#pragma unroll
    for (int mt = 0; mt < 4; ++mt)
#pragma unroll
      for (int nt = 0; nt < 4; ++nt)
        acc[mt][nt] = __builtin_amdgcn_mfma_f32_16x16x32_bf16(af[mt], bfr[nt], acc[mt][nt], 0, 0, 0);
    __syncthreads();
  }
#pragma unroll
  for (int nt = 0; nt < 4; ++nt) {
    int gc = g0 + wn + nt * 16 + lo;
    float bv = bias[gc];
    int ws_ = (gc >> 4) & 7, mts = gc >> 7, his = (gc >> 2) & 3, rs = gc & 3;
    size_t gbase = ((size_t)(ws_ * 8 + mts) << 8) + (size_t)(his * 16) * 4 + rs;
#pragma unroll
    for (int mt = 0; mt < 4; ++mt) {
      size_t row = arow0 + wm + mt * 16 + hi * 4;
#pragma unroll
      for (int rr = 0; rr < 4; ++rr) {
        size_t rw = row + rr;
        int t = (int)(rw >> 8), ba = (int)(rw & 255);
        size_t e = ((size_t)(t * 16 + (ba >> 4)) << 14) + gbase + (size_t)(ba & 15) * 4;
        Cout[e] = f2b(acc[mt][nt][rr] + bv);
      }
    }
  }
}

// ---------------- persistent pipeline kernel (depth-3) ---------------------
__global__ __launch_bounds__(512, 2)
void lstm_persist(const int* __restrict__ x, const float* __restrict__ emb,
                  const u16* __restrict__ wih0b, const float* __restrict__ bc0,
                  const u16* __restrict__ whh0b, const u16* __restrict__ whh1b,
                  const u16* __restrict__ wih1b, const float* __restrict__ bc1,
                  u16* __restrict__ xpA0, u16* __restrict__ xpA1,
                  u16* __restrict__ xpB0, u16* __restrict__ xpB1,
                  u16* __restrict__ io0, u16* __restrict__ io1,
                  float* __restrict__ hs1, u32* __restrict__ bar,
                  int T, int nch) {
  extern __shared__ __align__(16) char smem[];
  int bid = blockIdx.x;
  int tid = threadIdx.x;

  if (bid >= NSCAN) {
    // ============== helper WGs: roleC (embed+gemmA) + gemmB per stage ======
    int team = tid >> 8, tt = tid & 255;
    char* Asm = smem + team * 40960;
    char* Bsm = Asm + 20480;
    int wq = tt >> 6, lq = tt & 63;
    int hiq = lq >> 4, loq = lq & 15;
    int wm = (wq >> 1) * 64, wn = (wq & 1) * 64;
    int r = tt >> 1, cp = tt & 1;
    int tg = (bid - NSCAN) * 2 + team;
    const int stride = NHELP * 2;                 // 192 teams
    int njobs = T * 16;
    int nIt = (njobs + stride - 1) / stride;

    for (int s = 0; s <= nch + 1; ++s) {
      // ---- roleC: chunk s+1 -> xpA[(s+1)&1] ----
      if (s + 1 < nch) {
        u16* xpC = ((s + 1) & 1) ? xpA1 : xpA0;
        int t0c = (s + 1) * T;
        for (int it = 0; it < nIt; ++it) {
          int j = tg + it * stride;
          bool act = j < njobs;
          int jj = act ? j : 0;
          int mblk = jj >> 3, nblk = jj & 7;
          size_t arow0 = (size_t)mblk * 128;
          int g0 = nblk * 128;
          f32x4 acc[4][4] = {};
          int rw = (int)(arow0 + r);
          int sl = rw >> 8, ba = rw & 255;
          int tok = x[ba * NS + t0c + sl];
          const float* erow = emb + (size_t)tok * NE;
          for (int k0 = 0; k0 < NE; k0 += 32) {
            const float* src = erow + k0 + cp * 16;
            u32 pk[8];
#pragma unroll
            for (int q = 0; q < 8; ++q) {
              float a = src[2 * q], b = src[2 * q + 1];
              if (tok == 0) { a = 0.0f; b = 0.0f; }
              pk[q] = (u32)f2b(a) | ((u32)f2b(b) << 16);
            }
            *(int4*)(Asm + r * 80 + cp * 32)      = *(int4*)&pk[0];
            *(int4*)(Asm + r * 80 + cp * 32 + 16) = *(int4*)&pk[4];
            int4 b0 = *(const int4*)(wih0b + (size_t)(g0 + r) * NE + k0 + cp * 16);
            int4 b1 = *(const int4*)(wih0b + (size_t)(g0 + r) * NE + k0 + cp * 16 + 8);
            *(int4*)(Bsm + r * 80 + cp * 32)      = b0;
            *(int4*)(Bsm + r * 80 + cp * 32 + 16) = b1;
            __syncthreads();
            short8 af[4], bfr[4];
#pragma unroll
            for (int mt = 0; mt < 4; ++mt)
              af[mt] = *(const short8*)(Asm + (wm + mt * 16 + loq) * 80 + hiq * 16);
#pragma unroll
            for (int nt = 0; nt < 4; ++nt)
              bfr[nt] = *(const short8*)(Bsm + (wn + nt * 16 + loq) * 80 + hiq * 16);
#pragma unroll
            for (int mt = 0; mt < 4; ++mt)
#pragma unroll
              for (int nt = 0; nt < 4; ++nt)
                acc[mt][nt] = __builtin_amdgcn_mfma_f32_16x16x32_bf16(af[mt], bfr[nt], acc[mt][nt], 0, 0, 0);
            __syncthreads();
          }
          if (act) {
#pragma unroll
            for (int nt = 0; nt < 4; ++nt) {
              int gc = g0 + wn + nt * 16 + loq;
              float bv = bc0[gc];
              int ws_ = (gc >> 4) & 7, mts = gc >> 7, his = (gc >> 2) & 3, rs = gc & 3;
              size_t gbase = ((size_t)(ws_ * 8 + mts) << 8) + (size_t)(his * 16) * 4 + rs;
#pragma unroll
              for (int mt = 0; mt < 4; ++mt) {
                size_t row = arow0 + wm + mt * 16 + hiq * 4;
#pragma unroll
                for (int rr = 0; rr < 4; ++rr) {
                  size_t rw2 = row + rr;
                  int t = (int)(rw2 >> 8), ba2 = (int)(rw2 & 255);
                  size_t e = ((size_t)(t * 16 + (ba2 >> 4)) << 14) + gbase + (size_t)(ba2 & 15) * 4;
                  xpC[e] = f2b(acc[mt][nt][rr] + bv);
                }
              }
            }
          }
        }
      }
      // ---- gemmB: chunk s-1, io[(s-1)&1] -> xpB[(s-1)&1] ----
      if (s >= 1 && s <= nch) {
        const u16* hsrc = ((s - 1) & 1) ? io1 : io0;
        u16* xdst = ((s - 1) & 1) ? xpB1 : xpB0;
        for (int it = 0; it < nIt; ++it) {
          int j = tg + it * stride;
          bool act = j < njobs;
          int jj = act ? j : 0;
          int mblk = jj >> 3, nblk = jj & 7;
          size_t arow0 = (size_t)mblk * 128;
          int g0 = nblk * 128;
          f32x4 acc[4][4] = {};
          for (int k0 = 0; k0 < NH; k0 += 32) {
            int4 a0 = *(const int4*)(hsrc + (arow0 + r) * NH + k0 + cp * 16);
            int4 a1 = *(const int4*)(hsrc + (arow0 + r) * NH + k0 + cp * 16 + 8);
            int4 b0 = *(const int4*)(wih1b + (size_t)(g0 + r) * NH + k0 + cp * 16);
            int4 b1 = *(const int4*)(wih1b + (size_t)(g0 + r) * NH + k0 + cp * 16 + 8);
            *(int4*)(Asm + r * 80 + cp * 32)      = a0;
            *(int4*)(Asm + r * 80 + cp * 32 + 16) = a1;
            *(int4*)(Bsm + r * 80 + cp * 32)      = b0;
            *(int4*)(Bsm + r * 80 + cp * 32 + 16) = b1;
            __syncthreads();
            short8 af[4], bfr[4];
#pragma unroll
            for (int mt = 0; mt < 4; ++mt)
              af[mt] = *(const short8*)(Asm + (wm + mt * 16 + loq) * 80 + hiq * 16);
#pragma unroll
            for (int nt = 0; nt < 4; ++nt)
              bfr[nt] = *(const short8*)(Bsm + (wn + nt * 16 + loq) * 80 + hiq * 16);
#pragma unroll
            for (int mt = 0; mt < 4; ++mt)
#pragma unroll
              for (int nt = 0; nt < 4; ++nt)
                acc[mt][nt] = __builtin_amdgcn_mfma_f32_16x16x32_bf16(af[mt], bfr[nt], acc[mt][nt], 0, 0, 0);
            __syncthreads();
          }
          if (act) {
#pragma unroll
            for (int nt = 0; nt < 4; ++nt) {
              int gc = g0 + wn + nt * 16 + loq;
              float bv = bc1[gc];
              int ws_ = (gc >> 4) & 7, mts = gc >> 7, his = (gc >> 2) & 3, rs = gc & 3;
              size_t gbase = ((size_t)(ws_ * 8 + mts) << 8) + (size_t)(his * 16) * 4 + rs;
#pragma unroll
              for (int mt = 0; mt < 4; ++mt) {
                size_t row = arow0 + wm + mt * 16 + hiq * 4;
#pragma unroll
                for (int rr = 0; rr < 4; ++rr) {
                  size_t rw2 = row + rr;
                  int t = (int)(rw2 >> 8), ba2 = (int)(rw2 & 255);
                  size_t e = ((size_t)(t * 16 + (ba2 >> 4)) << 14) + gbase + (size_t)(ba2 & 15) * 4;
                  xdst[e] = f2b(acc[mt][nt][rr] + bv);
                }
              }
            }
          }
        }
      }
      if (s <= nch) gbar(bar, s, tid, bid);
    }
    return;
  }

  // ============== scan WGs: roleA (L0, chunk s) / roleB (L1, chunk s-2) ====
  int roleB = bid >> 4;
  int bgi = bid & 15;
  int bg = bgi * 16;
  const u16* whh = roleB ? whh1b : whh0b;

  int w = tid >> 6, l = tid & 63;
  int hi = l >> 4, lo = l & 15;

  // ---- load Whh into regs + LDS (ONCE) ----
  int wbase = w * (WLDS_FRAGS * 1024) + l * 16;
  short8 wfv[8][5];
  short8 wfv2[6];
#pragma unroll
  for (int mt = 0; mt < 8; ++mt) {
#pragma unroll
    for (int p = 0; p < 8; ++p) {
      const u16* src = whh + (size_t)(16 * (w + 8 * mt) + lo) * NH + p * 32 + hi * 8;
      short8 v = *(const short8*)src;
      if (p < 2)                 *(short8*)(smem + wbase + (p * 8 + mt) * 1024) = v;
      else if (p == 2 && mt < 2) *(short8*)(smem + wbase + (16 + mt) * 1024) = v;
      else if (p == 2)           wfv2[mt - 2] = v;
      else                       wfv[mt][p - 3] = v;
    }
  }
  // ---- init h = 0 (LDS buffer 0), c = 0 (ONCE) ----
  float c[2][4];
  for (int i = tid; i < 16 * NH / 2; i += 512) ((u32*)(smem + HOFF))[i] = 0;
#pragma unroll
  for (int g = 0; g < 2; ++g)
#pragma unroll
    for (int r = 0; r < 4; ++r) c[g][r] = 0.0f;
  __syncthreads();

  // ---- step-invariant offsets ----
  int rdoff = (l ^ ((l >> 3) & 7)) * 16;
  int wroff[2];
#pragma unroll
  for (int g = 0; g < 2; ++g) {
    int xx = (2 * (w & 1) + (hi >> 1)) * 16 + lo;
    wroff[g] = (4 * g + (w >> 1)) * 1024 + (xx ^ ((xx >> 3) & 7)) * 16 + 8 * (hi & 1);
  }
  int bq = tid >> 5, kc = tid & 31;
  int xw = (kc & 3) * 16 + bq;
  int wboff = (kc >> 2) * 1024 + (xw ^ ((xw >> 3) & 7)) * 16;
  size_t wb_glob = (size_t)(bg + bq) * NH + kc * 8;

  f32x4 acc[8];
  for (int s = 0; s <= nch + 1; ++s) {
    bool act = roleB ? (s >= 2) : (s < nch);
    if (act) {
      int mc = roleB ? (s - 2) : s;
      const u16* xp = roleB ? ((mc & 1) ? xpB1 : xpB0)
                            : ((mc & 1) ? xpA1 : xpA0);
      u16* hout = roleB ? (u16*)0 : ((s & 1) ? io1 : io0);
      const u16* xpp = xp + ((size_t)(bgi * 8 + w) * 2048) + (size_t)l * 4;
      ushort4 xq[8];
#pragma unroll
      for (int mt = 0; mt < 8; ++mt) xq[mt] = *(const ushort4*)(xpp + mt * 256);

      for (int t = 0; t < T; ++t) {
        int rbase = HOFF + ((t & 1) << 13);
        int wbbase = HOFF + ((~t & 1) << 13);
#pragma unroll
        for (int mt = 0; mt < 8; ++mt) {
          f32x4 a;
          a[0] = b2f(xq[mt].x); a[1] = b2f(xq[mt].y);
          a[2] = b2f(xq[mt].z); a[3] = b2f(xq[mt].w);
          acc[mt] = a;
        }
        xpp += 262144;   // next t (final overrun: adjacent ws buffer, discarded)
#pragma unroll
        for (int mt = 0; mt < 8; ++mt) xq[mt] = *(const ushort4*)(xpp + mt * 256);
#pragma unroll
        for (int p = 0; p < 8; ++p) {
          short8 bf = *(const short8*)(smem + rbase + rdoff + p * 1024);
#pragma unroll
          for (int mt = 0; mt < 8; ++mt) {
            short8 af;
            if (p < 2)                 af = *(const short8*)(smem + wbase + (p * 8 + mt) * 1024);
            else if (p == 2 && mt < 2) af = *(const short8*)(smem + wbase + (16 + mt) * 1024);
            else if (p == 2)           af = wfv2[mt - 2];
            else                       af = wfv[mt][p - 3];
            acc[mt] = __builtin_amdgcn_mfma_f32_16x16x32_bf16(af, bf, acc[mt], 0, 0, 0);
          }
        }
#pragma unroll
        for (int g = 0; g < 2; ++g) {
          float hv[4];
#pragma unroll
          for (int r = 0; r < 4; ++r) {
            float iv = rcpa(1.0f + ex2n(acc[g][r]));
            float fv = rcpa(1.0f + ex2n(acc[2 + g][r]));
            float gv = 1.0f - 2.0f * rcpa(ex2(acc[4 + g][r]) + 1.0f);
            float ov = rcpa(1.0f + ex2n(acc[6 + g][r]));
            float cc = fv * c[g][r] + iv * gv;
            c[g][r] = cc;
            float th = 1.0f - 2.0f * rcpa(ex2(cc * TWO_L2E) + 1.0f);
            hv[r] = ov * th;
          }
          u32 d0, d1;
          asm("v_cvt_pk_bf16_f32 %0, %1, %2" : "=v"(d0) : "v"(hv[0]), "v"(hv[1]));
          asm("v_cvt_pk_bf16_f32 %0, %1, %2" : "=v"(d1) : "v"(hv[2]), "v"(hv[3]));
          uint2 hw; hw.x = d0; hw.y = d1;
          *(uint2*)(smem + wbbase + wroff[g]) = hw;
        }
        __syncthreads();
        if (hout) {
          int4 hv4 = *(const int4*)(smem + wbbase + wboff);
          *(int4*)(hout + wb_glob + ((size_t)t << 16)) = hv4;
        }
      }
    }
    if (s <= nch) gbar(bar, s, tid, bid);
  }

  // ---- roleB: final h -> hs1 (T even => final h in buffer 0) ----
  if (roleB) {
#pragma unroll
    for (int g = 0; g < 2; ++g) {
      ushort4 hv4 = *(const ushort4*)(smem + HOFF + wroff[g]);
      int j = 16 * w + 128 * g + 4 * hi;
      u16 hb[4] = {hv4.x, hv4.y, hv4.z, hv4.w};
#pragma unroll
      for (int r = 0; r < 4; ++r)
        hs1[(size_t)(bg + lo) * NH + j + r] = b2f(hb[r]);
    }
  }
}

// ---------------- LayerNorm + projection -----------------------------------
__global__ __launch_bounds__(256) void ln_proj(const float* __restrict__ hn,
                                               const float* __restrict__ lng,
                                               const float* __restrict__ lnb,
                                               const float* __restrict__ pW,
                                               const float* __restrict__ pb,
                                               float* __restrict__ out) {
  __shared__ __align__(16) float nbuf[NH];
  __shared__ float red[8];
  int b = blockIdx.x, tid = threadIdx.x;
  float v = hn[(size_t)b * NH + tid];
  float s = v, s2 = v * v;
#pragma unroll
  for (int o = 32; o > 0; o >>= 1) {
    s  += __shfl_down(s, o);
    s2 += __shfl_down(s2, o);
  }
  if ((tid & 63) == 0) { red[tid >> 6] = s; red[4 + (tid >> 6)] = s2; }
  __syncthreads();
  if (tid == 0) {
    red[0] = red[0] + red[1] + red[2] + red[3];
    red[4] = red[4] + red[5] + red[6] + red[7];
  }
  __syncthreads();
  float mean = red[0] * (1.0f / NH);
  float var  = red[4] * (1.0f / NH) - mean * mean;
  float rs = rsqrtf(var + 1e-5f);
  nbuf[tid] = (v - mean) * rs * lng[tid] + lnb[tid];
  __syncthreads();
  if (tid < NE) {
    float a = pb[tid];
    const float* wr = pW + (size_t)tid * NH;
#pragma unroll 4
    for (int j = 0; j < NH; ++j) a = fmaf(nbuf[j], wr[j], a);
    out[(size_t)b * NE + tid] = a;
  }
}

// ---------------------------------------------------------------------------
extern "C" void kernel_launch(void* const* d_in, const int* in_sizes, int n_in,
                              void* d_out, int out_size, void* d_ws, size_t ws_size,
                              hipStream_t stream) {
  const int*   x     = (const int*)d_in[0];
  const float* emb   = (const float*)d_in[1];
  const float* Wih0  = (const float*)d_in[2];
  const float* Whh0  = (const float*)d_in[3];
  const float* bih0  = (const float*)d_in[4];
  const float* bhh0  = (const float*)d_in[5];
  const float* Wih1  = (const float*)d_in[6];
  const float* Whh1  = (const float*)d_in[7];
  const float* bih1  = (const float*)d_in[8];
  const float* bhh1  = (const float*)d_in[9];
  const float* ln_g  = (const float*)d_in[10];
  const float* ln_b  = (const float*)d_in[11];
  const float* projW = (const float*)d_in[12];
  const float* projb = (const float*)d_in[13];

  hipFuncSetAttribute((const void*)lstm_persist,
                      hipFuncAttributeMaxDynamicSharedMemorySize, SCAN_LDS);

  // footprint: xpA0/xpA1/xpB0/xpB1 (4*T*524288) + io0/io1 (2*T*131072) + FIXED
  const size_t FIXED = 2400256;   // weights 1.84M + hs1 256K + bar 4K + pad
  int T = 64;
  while (T > 4 && FIXED + (size_t)T * 2359296 > ws_size) T >>= 1;
  int nch = NS / T;

  char* ws = (char*)d_ws;
  u16*   xpA0  = (u16*)(ws);
  u16*   xpA1  = (u16*)(ws + (size_t)T * 524288);
  u16*   xpB0  = (u16*)(ws + (size_t)T * 1048576);
  u16*   xpB1  = (u16*)(ws + (size_t)T * 1572864);
  u16*   io0   = (u16*)(ws + (size_t)T * 2097152);
  u16*   io1   = (u16*)(ws + (size_t)T * 2228224);
  char*  wbase = ws + (size_t)T * 2359296;
  u16*   wih0b = (u16*)(wbase);
  u16*   whh0b = (u16*)(wbase + 262144);
  u16*   wih1b = (u16*)(wbase + 786432);
  u16*   whh1b = (u16*)(wbase + 1310720);
  float* bc0   = (float*)(wbase + 1835008);
  float* bc1   = (float*)(wbase + 1839104);
  float* hs1   = (float*)(wbase + 1843200);
  u32*   bar   = (u32*)(wbase + 2105344);            // 8 lines x 128B

  zero_flags<<<4, 256, 0, stream>>>(bar, 1024);
  prep_weights<<<256, 256, 0, stream>>>(Wih0, Whh0, bih0, bhh0, Wih1, Whh1, bih1, bhh1,
                                        wih0b, whh0b, wih1b, whh1b, bc0, bc1);
  // prologue: xpA0 for L0 chunk 0 (ebuf staged in xpB0, overwritten later)
  embed_chunk<<<T * 32, 256, 0, stream>>>(x, emb, xpB0, 0);
  xp_gemm<NE><<<T * 16, 256, 0, stream>>>(xpB0, wih0b, bc0, xpA0);

  lstm_persist<<<NWG, 512, SCAN_LDS, stream>>>(
      x, emb, wih0b, bc0, whh0b, whh1b, wih1b, bc1,
      xpA0, xpA1, xpB0, xpB1, io0, io1, hs1, bar, T, nch);

  ln_proj<<<NB, 256, 0, stream>>>(hs1, ln_g, ln_b, projW, projb, (float*)d_out);
}

// Round 18
// 1369.117 us; speedup vs baseline: 3.1823x; 1.0168x over previous
//
#include <hip/hip_runtime.h>
#include <hip/hip_bf16.h>

// ---------------------------------------------------------------------------
// 2-layer LSTM (B=256,S=512,E=128,H=256) + LayerNorm + projection.
// Round 17: dataflow counters instead of a global barrier. R16's residual
// (~32us/stage) = per-stage max-of-32 scan skew + 2 fences/WG/stage forced
// by the all-WG barrier. Now 3 monotonic counters (CA/CB/CH): scans wait
// only on helpers (who finish early -> near-zero wait), helpers wait on
// scans (off critical path). All buffer hazards (io/xpA/xpB parity dbufs)
// verified against counter targets; no wait cycles.
//   scanA chunk s:  wait CH>=96s;  run; signal CA (release: io stores)
//   scanB stage q:  wait CH>=96q;  run chunk q-2; signal CB (no release)
//   helpers stage s: wait CA>=16s; roleC(s+1); wait CB>=16(s-2); gemmB(s-1);
//                    signal CH (release: xpA/xpB stores)
// Scan math verbatim R9-R16 (passed, absmax 0.0156).
// ---------------------------------------------------------------------------

typedef unsigned short u16;
typedef unsigned int   u32;
using short8 = __attribute__((ext_vector_type(8))) short;
using f32x4  = __attribute__((ext_vector_type(4))) float;

#define NB 256
#define NS 512
#define NE 128
#define NH 256
#define NG 1024  // 4*H

#define WLDS_FRAGS 18
#define HOFF 147456
#define SCAN_LDS (HOFF + 2 * 16 * NH * 2)   // 163840 = 160 KiB

#define NSCAN 32
#define NHELP 96
#define NWG   (NSCAN + NHELP)   // 128 <= 256 CUs @ 160KB LDS: co-resident

#define L2E     1.4426950408889634f
#define TWO_L2E 2.8853900817779268f

__device__ __forceinline__ u16 f2b(float x) {
  __hip_bfloat16 h = __float2bfloat16(x);
  return __builtin_bit_cast(u16, h);
}
__device__ __forceinline__ float b2f(u16 u) {
  return __builtin_bit_cast(float, (u32)u << 16);
}
__device__ __forceinline__ float ex2(float x)  { return __builtin_amdgcn_exp2f(x); }
__device__ __forceinline__ float ex2n(float x) { return __builtin_amdgcn_exp2f(-x); }
__device__ __forceinline__ float rcpa(float x) { return __builtin_amdgcn_rcpf(x); }

// ---- dataflow sync primitives (R15/R16-validated fence pattern) ----
// signal: WG-wide drain (vmcnt(0) at barrier), optional release fence, add.
__device__ __forceinline__ void sigCtr(u32* c, int tid, bool rel) {
  __syncthreads();
  if (tid == 0) {
    if (rel) __threadfence();          // release: publish stores (wbL2 once)
    __hip_atomic_fetch_add(c, 1u, __ATOMIC_RELAXED, __HIP_MEMORY_SCOPE_AGENT);
  }
}
// wait: relaxed poll (no per-poll L2 invalidate), acquire fence once on exit.
__device__ __forceinline__ void waitCtr(u32* c, int target, int tid) {
  if (target <= 0) return;
  if (tid == 0) {
    while ((int)__hip_atomic_load(c, __ATOMIC_RELAXED, __HIP_MEMORY_SCOPE_AGENT) < target)
      __builtin_amdgcn_s_sleep(4);
    __threadfence();                   // acquire: refresh caches (once)
  }
  __syncthreads();
}

// ---------------- prep: fp32 weights -> bf16 (exp2-prescaled), biases ------
__global__ __launch_bounds__(256) void prep_weights(
    const float* Wih0, const float* Whh0, const float* bih0, const float* bhh0,
    const float* Wih1, const float* Whh1, const float* bih1, const float* bhh1,
    u16* wih0b, u16* whh0b, u16* wih1b, u16* whh1b, float* bc0, float* bc1) {
  int stride = gridDim.x * blockDim.x;
  int tid = blockIdx.x * blockDim.x + threadIdx.x;
  for (int i = tid; i < NG * NE; i += stride) {
    float s = (((i >> 7) >> 8) == 2) ? TWO_L2E : L2E;
    wih0b[i] = f2b(Wih0[i] * s);
  }
  for (int i = tid; i < NG * NH; i += stride) {
    float s = (((i >> 8) >> 8) == 2) ? TWO_L2E : L2E;
    whh0b[i] = f2b(Whh0[i] * s);
    wih1b[i] = f2b(Wih1[i] * s);
    whh1b[i] = f2b(Whh1[i] * s);
  }
  for (int i = tid; i < NG; i += stride) {
    float s = ((i >> 8) == 2) ? TWO_L2E : L2E;
    bc0[i] = (bih0[i] + bhh0[i]) * s;
    bc1[i] = (bih1[i] + bhh1[i]) * s;
  }
}

__global__ __launch_bounds__(256) void zero_flags(u32* f, int n) {
  int i = blockIdx.x * 256 + threadIdx.x;
  if (i < n) f[i] = 0;
}

// ---------------- embedding gather (prologue chunk 0 only) -----------------
__global__ __launch_bounds__(256) void embed_chunk(const int* __restrict__ x,
                                                   const float* __restrict__ emb,
                                                   u16* __restrict__ ebuf, int t0) {
  int gid = blockIdx.x * 256 + threadIdx.x;
  int d4 = gid & 31;
  int sb = gid >> 5;
  int b  = sb & (NB - 1);
  int sl = sb >> 8;
  int tok = x[b * NS + (t0 + sl)];
  float4 v = make_float4(0.f, 0.f, 0.f, 0.f);
  if (tok != 0) v = *(const float4*)(emb + (size_t)tok * NE + d4 * 4);
  ushort4 o;
  o.x = f2b(v.x); o.y = f2b(v.y); o.z = f2b(v.z); o.w = f2b(v.w);
  *(ushort4*)(ebuf + (size_t)sb * NE + d4 * 4) = o;
}

// ---------------- xp GEMM (prologue chunk 0 only) --------------------------
template <int K>
__global__ __launch_bounds__(256) void xp_gemm(const u16* __restrict__ A,
                                               const u16* __restrict__ W,
                                               const float* __restrict__ bias,
                                               u16* __restrict__ Cout) {
  __shared__ __align__(16) char lds[2 * 128 * 80];
  char* Asm = lds;
  char* Bsm = lds + 128 * 80;
  int tid = threadIdx.x;
  int w = tid >> 6, l = tid & 63;
  int hi = l >> 4, lo = l & 15;
  int mblk = blockIdx.x >> 3, nblk = blockIdx.x & 7;
  size_t arow0 = (size_t)mblk * 128;
  int g0 = nblk * 128;
  int wm = (w >> 1) * 64, wn = (w & 1) * 64;
  f32x4 acc[4][4] = {};
  int r = tid >> 1, cp = tid & 1;

  for (int k0 = 0; k0 < K; k0 += 32) {
    int4 a0 = *(const int4*)(A + (arow0 + r) * K + k0 + cp * 16);
    int4 a1 = *(const int4*)(A + (arow0 + r) * K + k0 + cp * 16 + 8);
    int4 b0 = *(const int4*)(W + (size_t)(g0 + r) * K + k0 + cp * 16);
    int4 b1 = *(const int4*)(W + (size_t)(g0 + r) * K + k0 + cp * 16 + 8);
    *(int4*)(Asm + r * 80 + cp * 32)      = a0;
    *(int4*)(Asm + r * 80 + cp * 32 + 16) = a1;
    *(int4*)(Bsm + r * 80 + cp * 32)      = b0;
    *(int4*)(Bsm + r * 80 + cp * 32 + 16) = b1;
    __syncthreads();
    short8 af[4], bfr[4];
#pragma unroll
    for (int mt = 0; mt < 4; ++mt)
      af[mt] = *(const short8*)(Asm + (wm + mt * 16 + lo) * 80 + hi * 16);
#pragma unroll
    for (int nt = 0; nt < 4; ++nt)
      bfr[nt] = *(const short8*)(Bsm + (wn + nt * 16 + lo) * 80 + hi * 16);
#pragma unroll
    for (int mt = 0; mt < 4; ++mt)
#pragma unroll
      for (int nt = 0; nt < 4; ++nt)
        acc[mt][nt] = __builtin_amdgcn_mfma_f32_16x16x32_bf16(af[mt], bfr[nt], acc[mt][nt], 0, 0, 0);
    __syncthreads();
  }
#pragma unroll
  for (int nt = 0; nt < 4; ++nt) {
    int gc = g0 + wn + nt * 16 + lo;
    float bv = bias[gc];
    int ws_ = (gc >> 4) & 7, mts = gc >> 7, his = (gc >> 2) & 3, rs = gc & 3;
    size_t gbase = ((size_t)(ws_ * 8 + mts) << 8) + (size_t)(his * 16) * 4 + rs;
#pragma unroll
    for (int mt = 0; mt < 4; ++mt) {
      size_t row = arow0 + wm + mt * 16 + hi * 4;
#pragma unroll
      for (int rr = 0; rr < 4; ++rr) {
        size_t rw = row + rr;
        int t = (int)(rw >> 8), ba = (int)(rw & 255);
        size_t e = ((size_t)(t * 16 + (ba >> 4)) << 14) + gbase + (size_t)(ba & 15) * 4;
        Cout[e] = f2b(acc[mt][nt][rr] + bv);
      }
    }
  }
}

// ---------------- persistent pipeline kernel (dataflow) --------------------
__global__ __launch_bounds__(512, 2)
void lstm_persist(const int* __restrict__ x, const float* __restrict__ emb,
                  const u16* __restrict__ wih0b, const float* __restrict__ bc0,
                  const u16* __restrict__ whh0b, const u16* __restrict__ whh1b,
                  const u16* __restrict__ wih1b, const float* __restrict__ bc1,
                  u16* __restrict__ xpA0, u16* __restrict__ xpA1,
                  u16* __restrict__ xpB0, u16* __restrict__ xpB1,
                  u16* __restrict__ io0, u16* __restrict__ io1,
                  float* __restrict__ hs1, u32* __restrict__ bar,
                  int T, int nch) {
  extern __shared__ __align__(16) char smem[];
  int bid = blockIdx.x;
  int tid = threadIdx.x;
  u32* CA = bar;            // scanA chunk completions (16/stage)
  u32* CB = bar + 32;       // scanB chunk completions (16/stage)
  u32* CH = bar + 64;       // helper stage completions (96/stage)

  if (bid >= NSCAN) {
    // ============== helper WGs: roleC (embed+gemmA) + gemmB per stage ======
    int team = tid >> 8, tt = tid & 255;
    char* Asm = smem + team * 40960;
    char* Bsm = Asm + 20480;
    int wq = tt >> 6, lq = tt & 63;
    int hiq = lq >> 4, loq = lq & 15;
    int wm = (wq >> 1) * 64, wn = (wq & 1) * 64;
    int r = tt >> 1, cp = tt & 1;
    int tg = (bid - NSCAN) * 2 + team;
    const int stride = NHELP * 2;                 // 192 teams
    int njobs = T * 16;
    int nIt = (njobs + stride - 1) / stride;

    for (int s = 0; s <= nch; ++s) {
      waitCtr(CA, 16 * s, tid);        // io(s-1) RAW + xpA[(s+1)&1] WAR
      // ---- roleC: chunk s+1 -> xpA[(s+1)&1] ----
      if (s + 1 < nch) {
        u16* xpC = ((s + 1) & 1) ? xpA1 : xpA0;
        int t0c = (s + 1) * T;
        for (int it = 0; it < nIt; ++it) {
          int j = tg + it * stride;
          bool act = j < njobs;
          int jj = act ? j : 0;
          int mblk = jj >> 3, nblk = jj & 7;
          size_t arow0 = (size_t)mblk * 128;
          int g0 = nblk * 128;
          f32x4 acc[4][4] = {};
          int rw = (int)(arow0 + r);
          int sl = rw >> 8, ba = rw & 255;
          int tok = x[ba * NS + t0c + sl];
          const float* erow = emb + (size_t)tok * NE;
          for (int k0 = 0; k0 < NE; k0 += 32) {
            const float* src = erow + k0 + cp * 16;
            u32 pk[8];
#pragma unroll
            for (int q = 0; q < 8; ++q) {
              float a = src[2 * q], b = src[2 * q + 1];
              if (tok == 0) { a = 0.0f; b = 0.0f; }
              pk[q] = (u32)f2b(a) | ((u32)f2b(b) << 16);
            }
            *(int4*)(Asm + r * 80 + cp * 32)      = *(int4*)&pk[0];
            *(int4*)(Asm + r * 80 + cp * 32 + 16) = *(int4*)&pk[4];
            int4 b0 = *(const int4*)(wih0b + (size_t)(g0 + r) * NE + k0 + cp * 16);
            int4 b1 = *(const int4*)(wih0b + (size_t)(g0 + r) * NE + k0 + cp * 16 + 8);
            *(int4*)(Bsm + r * 80 + cp * 32)      = b0;
            *(int4*)(Bsm + r * 80 + cp * 32 + 16) = b1;
            __syncthreads();
            short8 af[4], bfr[4];
#pragma unroll
            for (int mt = 0; mt < 4; ++mt)
              af[mt] = *(const short8*)(Asm + (wm + mt * 16 + loq) * 80 + hiq * 16);
#pragma unroll
            for (int nt = 0; nt < 4; ++nt)
              bfr[nt] = *(const short8*)(Bsm + (wn + nt * 16 + loq) * 80 + hiq * 16);
#pragma unroll
            for (int mt = 0; mt < 4; ++mt)
#pragma unroll
              for (int nt = 0; nt < 4; ++nt)
                acc[mt][nt] = __builtin_amdgcn_mfma_f32_16x16x32_bf16(af[mt], bfr[nt], acc[mt][nt], 0, 0, 0);
            __syncthreads();
          }
          if (act) {
#pragma unroll
            for (int nt = 0; nt < 4; ++nt) {
              int gc = g0 + wn + nt * 16 + loq;
              float bv = bc0[gc];
              int ws_ = (gc >> 4) & 7, mts = gc >> 7, his = (gc >> 2) & 3, rs = gc & 3;
              size_t gbase = ((size_t)(ws_ * 8 + mts) << 8) + (size_t)(his * 16) * 4 + rs;
#pragma unroll
              for (int mt = 0; mt < 4; ++mt) {
                size_t row = arow0 + wm + mt * 16 + hiq * 4;
#pragma unroll
                for (int rr = 0; rr < 4; ++rr) {
                  size_t rw2 = row + rr;
                  int t = (int)(rw2 >> 8), ba2 = (int)(rw2 & 255);
                  size_t e = ((size_t)(t * 16 + (ba2 >> 4)) << 14) + gbase + (size_t)(ba2 & 15) * 4;
                  xpC[e] = f2b(acc[mt][nt][rr] + bv);
                }
              }
            }
          }
        }
      }
      // ---- gemmB: chunk s-1, io[(s-1)&1] -> xpB[(s-1)&1] ----
      waitCtr(CB, 16 * (s - 2), tid);  // xpB[(s-1)&1] WAR vs scanB(s-1)
      if (s >= 1) {
        const u16* hsrc = ((s - 1) & 1) ? io1 : io0;
        u16* xdst = ((s - 1) & 1) ? xpB1 : xpB0;
        for (int it = 0; it < nIt; ++it) {
          int j = tg + it * stride;
          bool act = j < njobs;
          int jj = act ? j : 0;
          int mblk = jj >> 3, nblk = jj & 7;
          size_t arow0 = (size_t)mblk * 128;
          int g0 = nblk * 128;
          f32x4 acc[4][4] = {};
          for (int k0 = 0; k0 < NH; k0 += 32) {
            int4 a0 = *(const int4*)(hsrc + (arow0 + r) * NH + k0 + cp * 16);
            int4 a1 = *(const int4*)(hsrc + (arow0 + r) * NH + k0 + cp * 16 + 8);
            int4 b0 = *(const int4*)(wih1b + (size_t)(g0 + r) * NH + k0 + cp * 16);
            int4 b1 = *(const int4*)(wih1b + (size_t)(g0 + r) * NH + k0 + cp * 16 + 8);
            *(int4*)(Asm + r * 80 + cp * 32)      = a0;
            *(int4*)(Asm + r * 80 + cp * 32 + 16) = a1;
            *(int4*)(Bsm + r * 80 + cp * 32)      = b0;
            *(int4*)(Bsm + r * 80 + cp * 32 + 16) = b1;
            __syncthreads();
            short8 af[4], bfr[4];
#pragma unroll
            for (int mt = 0; mt < 4; ++mt)
              af[mt] = *(const short8*)(Asm + (wm + mt * 16 + loq) * 80 + hiq * 16);
#pragma unroll
            for (int nt = 0; nt < 4; ++nt)
              bfr[nt] = *(const short8*)(Bsm + (wn + nt * 16 + loq) * 80 + hiq * 16);
#pragma unroll
            for (int mt = 0; mt < 4; ++mt)
#pragma unroll
              for (int nt = 0; nt < 4; ++nt)
                acc[mt][nt] = __builtin_amdgcn_mfma_f32_16x16x32_bf16(af[mt], bfr[nt], acc[mt][nt], 0, 0, 0);
            __syncthreads();
          }
          if (act) {
#pragma unroll
            for (int nt = 0; nt < 4; ++nt) {
              int gc = g0 + wn + nt * 16 + loq;
              float bv = bc1[gc];
              int ws_ = (gc >> 4) & 7, mts = gc >> 7, his = (gc >> 2) & 3, rs = gc & 3;
              size_t gbase = ((size_t)(ws_ * 8 + mts) << 8) + (size_t)(his * 16) * 4 + rs;
#pragma unroll
              for (int mt = 0; mt < 4; ++mt) {
                size_t row = arow0 + wm + mt * 16 + hiq * 4;
#pragma unroll
                for (int rr = 0; rr < 4; ++rr) {
                  size_t rw2 = row + rr;
                  int t = (int)(rw2 >> 8), ba2 = (int)(rw2 & 255);
                  size_t e = ((size_t)(t * 16 + (ba2 >> 4)) << 14) + gbase + (size_t)(ba2 & 15) * 4;
                  xdst[e] = f2b(acc[mt][nt][rr] + bv);
                }
              }
            }
          }
        }
      }
      sigCtr(CH, tid, true);           // release: xpA/xpB stores
    }
    return;
  }

  // ============== scan WGs: roleA (L0) / roleB (L1), persistent ============
  int roleB = bid >> 4;
  int bgi = bid & 15;
  int bg = bgi * 16;
  const u16* whh = roleB ? whh1b : whh0b;

  int w = tid >> 6, l = tid & 63;
  int hi = l >> 4, lo = l & 15;

  // ---- load Whh into regs + LDS (ONCE) ----
  int wbase = w * (WLDS_FRAGS * 1024) + l * 16;
  short8 wfv[8][5];
  short8 wfv2[6];
#pragma unroll
  for (int mt = 0; mt < 8; ++mt) {
#pragma unroll
    for (int p = 0; p < 8; ++p) {
      const u16* src = whh + (size_t)(16 * (w + 8 * mt) + lo) * NH + p * 32 + hi * 8;
      short8 v = *(const short8*)src;
      if (p < 2)                 *(short8*)(smem + wbase + (p * 8 + mt) * 1024) = v;
      else if (p == 2 && mt < 2) *(short8*)(smem + wbase + (16 + mt) * 1024) = v;
      else if (p == 2)           wfv2[mt - 2] = v;
      else                       wfv[mt][p - 3] = v;
    }
  }
  // ---- init h = 0 (LDS buffer 0), c = 0 (ONCE) ----
  float c[2][4];
  for (int i = tid; i < 16 * NH / 2; i += 512) ((u32*)(smem + HOFF))[i] = 0;
#pragma unroll
  for (int g = 0; g < 2; ++g)
#pragma unroll
    for (int r = 0; r < 4; ++r) c[g][r] = 0.0f;
  __syncthreads();

  // ---- step-invariant offsets ----
  int rdoff = (l ^ ((l >> 3) & 7)) * 16;
  int wroff[2];
#pragma unroll
  for (int g = 0; g < 2; ++g) {
    int xx = (2 * (w & 1) + (hi >> 1)) * 16 + lo;
    wroff[g] = (4 * g + (w >> 1)) * 1024 + (xx ^ ((xx >> 3) & 7)) * 16 + 8 * (hi & 1);
  }
  int bq = tid >> 5, kc = tid & 31;
  int xw = (kc & 3) * 16 + bq;
  int wboff = (kc >> 2) * 1024 + (xw ^ ((xw >> 3) & 7)) * 16;
  size_t wb_glob = (size_t)(bg + bq) * NH + kc * 8;

  f32x4 acc[8];
  int s0 = roleB ? 2 : 0;
  int s1 = roleB ? (nch + 1) : (nch - 1);
  for (int s = s0; s <= s1; ++s) {
    waitCtr(CH, 96 * s, tid);          // xp ready (RAW) + io free (WAR)
    {
      int mc = roleB ? (s - 2) : s;
      const u16* xp = roleB ? ((mc & 1) ? xpB1 : xpB0)
                            : ((mc & 1) ? xpA1 : xpA0);
      u16* hout = roleB ? (u16*)0 : ((s & 1) ? io1 : io0);
      const u16* xpp = xp + ((size_t)(bgi * 8 + w) * 2048) + (size_t)l * 4;
      ushort4 xq[8];
#pragma unroll
      for (int mt = 0; mt < 8; ++mt) xq[mt] = *(const ushort4*)(xpp + mt * 256);

      for (int t = 0; t < T; ++t) {
        int rbase = HOFF + ((t & 1) << 13);
        int wbbase = HOFF + ((~t & 1) << 13);
#pragma unroll
        for (int mt = 0; mt < 8; ++mt) {
          f32x4 a;
          a[0] = b2f(xq[mt].x); a[1] = b2f(xq[mt].y);
          a[2] = b2f(xq[mt].z); a[3] = b2f(xq[mt].w);
          acc[mt] = a;
        }
        xpp += 262144;   // next t (final overrun: adjacent ws buffer, discarded)
#pragma unroll
        for (int mt = 0; mt < 8; ++mt) xq[mt] = *(const ushort4*)(xpp + mt * 256);
#pragma unroll
        for (int p = 0; p < 8; ++p) {
          short8 bf = *(const short8*)(smem + rbase + rdoff + p * 1024);
#pragma unroll
          for (int mt = 0; mt < 8; ++mt) {
            short8 af;
            if (p < 2)                 af = *(const short8*)(smem + wbase + (p * 8 + mt) * 1024);
            else if (p == 2 && mt < 2) af = *(const short8*)(smem + wbase + (16 + mt) * 1024);
            else if (p == 2)           af = wfv2[mt - 2];
            else                       af = wfv[mt][p - 3];
            acc[mt] = __builtin_amdgcn_mfma_f32_16x16x32_bf16(af, bf, acc[mt], 0, 0, 0);
          }
        }
#pragma unroll
        for (int g = 0; g < 2; ++g) {
          float hv[4];
#pragma unroll
          for (int r = 0; r < 4; ++r) {
            float iv = rcpa(1.0f + ex2n(acc[g][r]));
            float fv = rcpa(1.0f + ex2n(acc[2 + g][r]));
            float gv = 1.0f - 2.0f * rcpa(ex2(acc[4 + g][r]) + 1.0f);
            float ov = rcpa(1.0f + ex2n(acc[6 + g][r]));
            float cc = fv * c[g][r] + iv * gv;
            c[g][r] = cc;
            float th = 1.0f - 2.0f * rcpa(ex2(cc * TWO_L2E) + 1.0f);
            hv[r] = ov * th;
          }
          u32 d0, d1;
          asm("v_cvt_pk_bf16_f32 %0, %1, %2" : "=v"(d0) : "v"(hv[0]), "v"(hv[1]));
          asm("v_cvt_pk_bf16_f32 %0, %1, %2" : "=v"(d1) : "v"(hv[2]), "v"(hv[3]));
          uint2 hw; hw.x = d0; hw.y = d1;
          *(uint2*)(smem + wbbase + wroff[g]) = hw;
        }
        __syncthreads();
        if (hout) {
          int4 hv4 = *(const int4*)(smem + wbbase + wboff);
          *(int4*)(hout + wb_glob + ((size_t)t << 16)) = hv4;
        }
      }
    }
    // scanA: release (io stores must be visible to gemmB); scanB: no stores
    sigCtr(roleB ? CB : CA, tid, !roleB);
  }

  // ---- roleB: final h -> hs1 (T even => final h in buffer 0) ----
  if (roleB) {
#pragma unroll
    for (int g = 0; g < 2; ++g) {
      ushort4 hv4 = *(const ushort4*)(smem + HOFF + wroff[g]);
      int j = 16 * w + 128 * g + 4 * hi;
      u16 hb[4] = {hv4.x, hv4.y, hv4.z, hv4.w};
#pragma unroll
      for (int r = 0; r < 4; ++r)
        hs1[(size_t)(bg + lo) * NH + j + r] = b2f(hb[r]);
    }
  }
}

// ---------------- LayerNorm + projection -----------------------------------
__global__ __launch_bounds__(256) void ln_proj(const float* __restrict__ hn,
                                               const float* __restrict__ lng,
                                               const float* __restrict__ lnb,
                                               const float* __restrict__ pW,
                                               const float* __restrict__ pb,
                                               float* __restrict__ out) {
  __shared__ __align__(16) float nbuf[NH];
  __shared__ float red[8];
  int b = blockIdx.x, tid = threadIdx.x;
  float v = hn[(size_t)b * NH + tid];
  float s = v, s2 = v * v;
#pragma unroll
  for (int o = 32; o > 0; o >>= 1) {
    s  += __shfl_down(s, o);
    s2 += __shfl_down(s2, o);
  }
  if ((tid & 63) == 0) { red[tid >> 6] = s; red[4 + (tid >> 6)] = s2; }
  __syncthreads();
  if (tid == 0) {
    red[0] = red[0] + red[1] + red[2] + red[3];
    red[4] = red[4] + red[5] + red[6] + red[7];
  }
  __syncthreads();
  float mean = red[0] * (1.0f / NH);
  float var  = red[4] * (1.0f / NH) - mean * mean;
  float rs = rsqrtf(var + 1e-5f);
  nbuf[tid] = (v - mean) * rs * lng[tid] + lnb[tid];
  __syncthreads();
  if (tid < NE) {
    float a = pb[tid];
    const float* wr = pW + (size_t)tid * NH;
#pragma unroll 4
    for (int j = 0; j < NH; ++j) a = fmaf(nbuf[j], wr[j], a);
    out[(size_t)b * NE + tid] = a;
  }
}

// ---------------------------------------------------------------------------
extern "C" void kernel_launch(void* const* d_in, const int* in_sizes, int n_in,
                              void* d_out, int out_size, void* d_ws, size_t ws_size,
                              hipStream_t stream) {
  const int*   x     = (const int*)d_in[0];
  const float* emb   = (const float*)d_in[1];
  const float* Wih0  = (const float*)d_in[2];
  const float* Whh0  = (const float*)d_in[3];
  const float* bih0  = (const float*)d_in[4];
  const float* bhh0  = (const float*)d_in[5];
  const float* Wih1  = (const float*)d_in[6];
  const float* Whh1  = (const float*)d_in[7];
  const float* bih1  = (const float*)d_in[8];
  const float* bhh1  = (const float*)d_in[9];
  const float* ln_g  = (const float*)d_in[10];
  const float* ln_b  = (const float*)d_in[11];
  const float* projW = (const float*)d_in[12];
  const float* projb = (const float*)d_in[13];

  hipFuncSetAttribute((const void*)lstm_persist,
                      hipFuncAttributeMaxDynamicSharedMemorySize, SCAN_LDS);

  // footprint: xpA0/xpA1/xpB0/xpB1 (4*T*524288) + io0/io1 (2*T*131072) + FIXED
  const size_t FIXED = 2400256;   // weights 1.84M + hs1 256K + bar 4K + pad
  int T = 64;
  while (T > 4 && FIXED + (size_t)T * 2359296 > ws_size) T >>= 1;
  int nch = NS / T;

  char* ws = (char*)d_ws;
  u16*   xpA0  = (u16*)(ws);
  u16*   xpA1  = (u16*)(ws + (size_t)T * 524288);
  u16*   xpB0  = (u16*)(ws + (size_t)T * 1048576);
  u16*   xpB1  = (u16*)(ws + (size_t)T * 1572864);
  u16*   io0   = (u16*)(ws + (size_t)T * 2097152);
  u16*   io1   = (u16*)(ws + (size_t)T * 2228224);
  char*  wbase = ws + (size_t)T * 2359296;
  u16*   wih0b = (u16*)(wbase);
  u16*   whh0b = (u16*)(wbase + 262144);
  u16*   wih1b = (u16*)(wbase + 786432);
  u16*   whh1b = (u16*)(wbase + 1310720);
  float* bc0   = (float*)(wbase + 1835008);
  float* bc1   = (float*)(wbase + 1839104);
  float* hs1   = (float*)(wbase + 1843200);
  u32*   bar   = (u32*)(wbase + 2105344);            // 3 lines x 128B

  zero_flags<<<4, 256, 0, stream>>>(bar, 1024);
  prep_weights<<<256, 256, 0, stream>>>(Wih0, Whh0, bih0, bhh0, Wih1, Whh1, bih1, bhh1,
                                        wih0b, whh0b, wih1b, whh1b, bc0, bc1);
  // prologue: xpA0 for L0 chunk 0 (ebuf staged in xpB0, overwritten later)
  embed_chunk<<<T * 32, 256, 0, stream>>>(x, emb, xpB0, 0);
  xp_gemm<NE><<<T * 16, 256, 0, stream>>>(xpB0, wih0b, bc0, xpA0);

  lstm_persist<<<NWG, 512, SCAN_LDS, stream>>>(
      x, emb, wih0b, bc0, whh0b, whh1b, wih1b, bc1,
      xpA0, xpA1, xpB0, xpB1, io0, io1, hs1, bar, T, nch);

  ln_proj<<<NB, 256, 0, stream>>>(hs1, ln_g, ln_b, projW, projb, (float*)d_out);
}